// Round 1
// baseline (2492.616 us; speedup 1.0000x reference)
//
#include <hip/hip_runtime.h>

#define NN 524288
#define NE 2097152
#define NG 16384
#define CDIM 3539
#define PDIM 384
#define GH 64
#define GE 128
#define HIDD 256
#define KD (GE + CDIM + PDIM)  // 4051

// ---------------- init: deg=1 (self-loop), zero pooling buffers ----------------
__global__ void k_init(float* __restrict__ deg, float* __restrict__ sums, float* __restrict__ cnt) {
    int i = blockIdx.x * blockDim.x + threadIdx.x;
    if (i < NN) deg[i] = 1.0f;
    if (i < NG * GH) sums[i] = 0.0f;
    if (i < NG) cnt[i] = 0.0f;
}

// ---------------- in-degree histogram over col ----------------
__global__ void k_deg(const int* __restrict__ ei, float* __restrict__ deg) {
    int e = blockIdx.x * blockDim.x + threadIdx.x;
    if (e < NE) atomicAdd(&deg[ei[NE + e]], 1.0f);
}

// ---------------- dinv = rsqrt(deg) in place; s init with self-loop term ----------------
__global__ void k_dinv_s(const float* __restrict__ node_x, float* __restrict__ deg, float* __restrict__ s) {
    int n = blockIdx.x * blockDim.x + threadIdx.x;
    if (n < NN) {
        float di = rsqrtf(deg[n]);
        deg[n] = di;  // deg buffer becomes dinv
        s[n] = di * di * node_x[n];
    }
}

// ---------------- layer-1 scalar scatter: s[c] += norm * node_x[r] ----------------
__global__ void k_s(const int* __restrict__ ei, const float* __restrict__ node_x,
                    const float* __restrict__ dinv, float* __restrict__ s) {
    int e = blockIdx.x * blockDim.x + threadIdx.x;
    if (e < NE) {
        int r = ei[e], c = ei[NE + e];
        atomicAdd(&s[c], dinv[r] * dinv[c] * node_x[r]);
    }
}

// ---------------- agg2 init with self-loop: agg2[n][j] = dinv[n]^2 * x1[n][j] ----------------
__global__ void k_agg_init(const float* __restrict__ s, const float* __restrict__ dinv,
                           const float* __restrict__ W1, const float* __restrict__ b1,
                           float* __restrict__ agg2) {
    int t = blockIdx.x * blockDim.x + threadIdx.x;  // NN*64 threads exactly
    int n = t >> 6, j = t & 63;
    float x1 = fmaxf(fmaf(s[n], W1[j], b1[j]), 0.0f);
    float di = dinv[n];
    agg2[t] = di * di * x1;
}

// ---------------- layer-2 edge scatter: wave per edge, lane = feature ----------------
__global__ void k_edge_scatter(const int* __restrict__ ei, const float* __restrict__ s,
                               const float* __restrict__ dinv, const float* __restrict__ W1,
                               const float* __restrict__ b1, float* __restrict__ agg2) {
    int gid = blockIdx.x * blockDim.x + threadIdx.x;  // NE*64 threads exactly
    int e = gid >> 6, j = gid & 63;
    int r = ei[e], c = ei[NE + e];
    float nrm = dinv[r] * dinv[c];
    float x1 = fmaxf(fmaf(s[r], W1[j], b1[j]), 0.0f);
    atomicAdd(&agg2[c * GH + j], nrm * x1);
}

// ---------------- per-node: x2 = relu(agg2 @ W2 + b2); pool into sums/cnt ----------------
__global__ void k_node(const float* __restrict__ agg2, const float* __restrict__ W2,
                       const float* __restrict__ b2, const int* __restrict__ batch,
                       float* __restrict__ sums, float* __restrict__ cnt) {
    __shared__ float w2s[GH * GH];   // 16 KB
    __shared__ float aggs[4 * GH];
    int t = threadIdx.x;
    for (int i = t; i < GH * GH; i += 256) w2s[i] = W2[i];
    int gid = blockIdx.x * 256 + t;  // NN*64 threads exactly
    int n = gid >> 6, j = t & 63, w = t >> 6;
    aggs[t] = agg2[gid];
    __syncthreads();
    float acc = b2[j];
#pragma unroll
    for (int k = 0; k < GH; k++) acc = fmaf(aggs[w * GH + k], w2s[k * GH + j], acc);
    float x2 = fmaxf(acc, 0.0f);
    int g = batch[n];
    atomicAdd(&sums[g * GH + j], x2);
    if (j == 0) atomicAdd(&cnt[g], 1.0f);
}

// ---------------- per-graph: pooled = sums/cnt; gemb = pooled @ Wg + bg ----------------
__global__ void k_graph(const float* __restrict__ sums, const float* __restrict__ cnt,
                        const float* __restrict__ Wg, const float* __restrict__ bg,
                        float* __restrict__ gemb) {
    __shared__ float wgs[GH * GE];   // 32 KB
    __shared__ float ps[4 * GH];
    int t = threadIdx.x;
    for (int i = t; i < GH * GE; i += 256) wgs[i] = Wg[i];
    int gid = blockIdx.x * 256 + t;  // NG*64 threads exactly
    int g = gid >> 6, j = t & 63, w = t >> 6;
    float c = fmaxf(cnt[g], 1.0f);
    ps[t] = sums[g * GH + j] / c;
    __syncthreads();
    float o0 = bg[j], o1 = bg[GH + j];
#pragma unroll
    for (int k = 0; k < GH; k++) {
        float p = ps[w * GH + k];
        o0 = fmaf(p, wgs[k * GE + j], o0);
        o1 = fmaf(p, wgs[k * GE + GH + j], o1);
    }
    gemb[g * GE + j] = o0;
    gemb[g * GE + GH + j] = o1;
}

// ---------------- big GEMM + relu + dot(Wf2) + sigmoid, fused ----------------
#define GB 32
#define TK 256
__global__ __launch_bounds__(256) void k_gemm(
        const float* __restrict__ gemb, const float* __restrict__ comp,
        const float* __restrict__ prot, const float* __restrict__ Wf1,
        const float* __restrict__ bf1, const float* __restrict__ Wf2,
        const float* __restrict__ bf2, float* __restrict__ out) {
    __shared__ float cl[GB * TK];   // 32 KB combined-tile
    __shared__ float red[GB];
    int o = threadIdx.x;            // output column 0..255
    int b0 = blockIdx.x * GB;
    float acc[GB];
#pragma unroll
    for (int g = 0; g < GB; g++) acc[g] = 0.0f;

    for (int k0 = 0; k0 < KD; k0 += TK) {
        __syncthreads();
        // stage combined[b0..b0+GB)[k0..k0+TK) into LDS (zero-padded past KD)
        for (int idx = o; idx < GB * TK; idx += 256) {
            int gl = idx >> 8;        // TK == 256
            int kl = idx & 255;
            int k = k0 + kl;
            int b = b0 + gl;
            float v = 0.0f;
            if (k < GE) v = gemb[b * GE + k];
            else if (k < GE + CDIM) v = comp[b * CDIM + (k - GE)];
            else if (k < KD) v = prot[b * PDIM + (k - GE - CDIM)];
            cl[idx] = v;
        }
        __syncthreads();
        for (int kk = 0; kk < TK; kk += 4) {
            int k = k0 + kk;
            // clamp index: cl is zero-padded past KD so contribution is 0 anyway
            float w0 = Wf1[min(k + 0, KD - 1) * HIDD + o];
            float w1 = Wf1[min(k + 1, KD - 1) * HIDD + o];
            float w2 = Wf1[min(k + 2, KD - 1) * HIDD + o];
            float w3 = Wf1[min(k + 3, KD - 1) * HIDD + o];
#pragma unroll
            for (int g = 0; g < GB; g++) {
                float4 c4 = *reinterpret_cast<const float4*>(&cl[g * TK + kk]);
                acc[g] = fmaf(c4.x, w0, acc[g]);
                acc[g] = fmaf(c4.y, w1, acc[g]);
                acc[g] = fmaf(c4.z, w2, acc[g]);
                acc[g] = fmaf(c4.w, w3, acc[g]);
            }
        }
    }

    float wf2 = Wf2[o];
    float bias1 = bf1[o];
    if (o < GB) red[o] = 0.0f;
    __syncthreads();
#pragma unroll
    for (int g = 0; g < GB; g++) {
        float h = fmaxf(acc[g] + bias1, 0.0f);
        float v = h * wf2;
#pragma unroll
        for (int off = 32; off > 0; off >>= 1) v += __shfl_down(v, off, 64);
        if ((threadIdx.x & 63) == 0) atomicAdd(&red[g], v);
    }
    __syncthreads();
    if (o < GB) out[b0 + o] = 1.0f / (1.0f + expf(-(red[o] + bf2[0])));
}

extern "C" void kernel_launch(void* const* d_in, const int* in_sizes, int n_in,
                              void* d_out, int out_size, void* d_ws, size_t ws_size,
                              hipStream_t stream) {
    const float* node_x = (const float*)d_in[0];
    const float* comp   = (const float*)d_in[1];
    const float* prot   = (const float*)d_in[2];
    const int*   ei     = (const int*)d_in[3];
    const int*   batch  = (const int*)d_in[4];
    const float* W1  = (const float*)d_in[5];
    const float* b1  = (const float*)d_in[6];
    const float* W2  = (const float*)d_in[7];
    const float* b2  = (const float*)d_in[8];
    const float* Wg  = (const float*)d_in[9];
    const float* bg  = (const float*)d_in[10];
    const float* Wf1 = (const float*)d_in[11];
    const float* bf1 = (const float*)d_in[12];
    const float* Wf2 = (const float*)d_in[13];
    const float* bf2 = (const float*)d_in[14];
    float* out = (float*)d_out;

    float* w    = (float*)d_ws;
    float* deg  = w;                         // NN floats (becomes dinv in place)
    float* s    = deg + NN;                  // NN
    float* agg2 = s + NN;                    // NN*64  (134 MB)
    float* sums = agg2 + (size_t)NN * GH;    // NG*64
    float* cnt  = sums + NG * GH;            // NG
    float* gemb = cnt + NG;                  // NG*128

    k_init<<<(NG * GH + 255) / 256, 256, 0, stream>>>(deg, sums, cnt);
    k_deg<<<NE / 256, 256, 0, stream>>>(ei, deg);
    k_dinv_s<<<NN / 256, 256, 0, stream>>>(node_x, deg, s);
    k_s<<<NE / 256, 256, 0, stream>>>(ei, node_x, deg, s);
    k_agg_init<<<(NN * GH) / 256, 256, 0, stream>>>(s, deg, W1, b1, agg2);
    k_edge_scatter<<<(NE * GH) / 256, 256, 0, stream>>>(ei, s, deg, W1, b1, agg2);
    k_node<<<(NN * GH) / 256, 256, 0, stream>>>(agg2, W2, b2, batch, sums, cnt);
    k_graph<<<(NG * GH) / 256, 256, 0, stream>>>(sums, cnt, Wg, bg, gemb);
    k_gemm<<<NG / GB, 256, 0, stream>>>(gemb, comp, prot, Wf1, bf1, Wf2, bf2, out);
}

// Round 2
// 1432.567 us; speedup vs baseline: 1.7400x; 1.7400x over previous
//
#include <hip/hip_runtime.h>

#define NN 524288
#define NE 2097152
#define NG 16384
#define CDIM 3539
#define PDIM 384
#define GH 64
#define GE 128
#define HIDD 256
#define KD (GE + CDIM + PDIM)  // 4051
#define KP 4096                // padded K stride (bf16 elems)
#define KLOOP 4064             // 127*32 >= KD, multiple of 32

typedef short bf16x8 __attribute__((ext_vector_type(8)));
typedef float f32x4 __attribute__((ext_vector_type(4)));

__device__ inline unsigned short f2bf(float f) {
    unsigned int u = __float_as_uint(f);
    u += 0x7FFF + ((u >> 16) & 1);  // RNE
    return (unsigned short)(u >> 16);
}

// ---------------- init: deg=1 (self-loop), zero pooling buffers ----------------
__global__ void k_init(float* __restrict__ deg, float* __restrict__ sums, float* __restrict__ cnt) {
    int i = blockIdx.x * blockDim.x + threadIdx.x;
    if (i < NN) deg[i] = 1.0f;
    if (i < NG * GH) sums[i] = 0.0f;
    if (i < NG) cnt[i] = 0.0f;
}

// ---------------- in-degree histogram over col ----------------
__global__ void k_deg(const int* __restrict__ ei, float* __restrict__ deg) {
    int e = blockIdx.x * blockDim.x + threadIdx.x;
    if (e < NE) atomicAdd(&deg[ei[NE + e]], 1.0f);
}

// ---------------- dinv = rsqrt(deg) in place; s init with self-loop term ----------------
__global__ void k_dinv_s(const float* __restrict__ node_x, float* __restrict__ deg, float* __restrict__ s) {
    int n = blockIdx.x * blockDim.x + threadIdx.x;
    if (n < NN) {
        float di = rsqrtf(deg[n]);
        deg[n] = di;  // deg buffer becomes dinv
        s[n] = di * di * node_x[n];
    }
}

// ---------------- layer-1 scalar scatter: s[c] += norm * node_x[r] ----------------
__global__ void k_s(const int* __restrict__ ei, const float* __restrict__ node_x,
                    const float* __restrict__ dinv, float* __restrict__ s) {
    int e = blockIdx.x * blockDim.x + threadIdx.x;
    if (e < NE) {
        int r = ei[e], c = ei[NE + e];
        atomicAdd(&s[c], dinv[r] * dinv[c] * node_x[r]);
    }
}

// ---------------- agg2 init with self-loop: agg2[n][j] = dinv[n]^2 * x1[n][j] ----------------
__global__ void k_agg_init(const float* __restrict__ s, const float* __restrict__ dinv,
                           const float* __restrict__ W1, const float* __restrict__ b1,
                           float* __restrict__ agg2) {
    int t = blockIdx.x * blockDim.x + threadIdx.x;  // NN*64 threads exactly
    int n = t >> 6, j = t & 63;
    float x1 = fmaxf(fmaf(s[n], W1[j], b1[j]), 0.0f);
    float di = dinv[n];
    agg2[t] = di * di * x1;
}

// ---------------- layer-2 edge scatter: wave per edge, lane = feature ----------------
__global__ void k_edge_scatter(const int* __restrict__ ei, const float* __restrict__ s,
                               const float* __restrict__ dinv, const float* __restrict__ W1,
                               const float* __restrict__ b1, float* __restrict__ agg2) {
    int gid = blockIdx.x * blockDim.x + threadIdx.x;  // NE*64 threads exactly
    int e = gid >> 6, j = gid & 63;
    int r = ei[e], c = ei[NE + e];
    float nrm = dinv[r] * dinv[c];
    float x1 = fmaxf(fmaf(s[r], W1[j], b1[j]), 0.0f);
    atomicAdd(&agg2[c * GH + j], nrm * x1);
}

// ---------------- per-node: x2 = relu(agg2 @ W2 + b2); pool into sums/cnt ----------------
__global__ void k_node(const float* __restrict__ agg2, const float* __restrict__ W2,
                       const float* __restrict__ b2, const int* __restrict__ batch,
                       float* __restrict__ sums, float* __restrict__ cnt) {
    __shared__ float w2s[GH * GH];   // 16 KB
    __shared__ float aggs[4 * GH];
    int t = threadIdx.x;
    for (int i = t; i < GH * GH; i += 256) w2s[i] = W2[i];
    int gid = blockIdx.x * 256 + t;  // NN*64 threads exactly
    int n = gid >> 6, j = t & 63, w = t >> 6;
    aggs[t] = agg2[gid];
    __syncthreads();
    float acc = b2[j];
#pragma unroll
    for (int k = 0; k < GH; k++) acc = fmaf(aggs[w * GH + k], w2s[k * GH + j], acc);
    float x2 = fmaxf(acc, 0.0f);
    int g = batch[n];
    atomicAdd(&sums[g * GH + j], x2);
    if (j == 0) atomicAdd(&cnt[g], 1.0f);
}

// ---------------- per-graph: pooled = sums/cnt; gemb = pooled @ Wg + bg ----------------
__global__ void k_graph(const float* __restrict__ sums, const float* __restrict__ cnt,
                        const float* __restrict__ Wg, const float* __restrict__ bg,
                        float* __restrict__ gemb) {
    __shared__ float wgs[GH * GE];   // 32 KB
    __shared__ float ps[4 * GH];
    int t = threadIdx.x;
    for (int i = t; i < GH * GE; i += 256) wgs[i] = Wg[i];
    int gid = blockIdx.x * 256 + t;  // NG*64 threads exactly
    int g = gid >> 6, j = t & 63, w = t >> 6;
    float c = fmaxf(cnt[g], 1.0f);
    ps[t] = sums[g * GH + j] / c;
    __syncthreads();
    float o0 = bg[j], o1 = bg[GH + j];
#pragma unroll
    for (int k = 0; k < GH; k++) {
        float p = ps[w * GH + k];
        o0 = fmaf(p, wgs[k * GE + j], o0);
        o1 = fmaf(p, wgs[k * GE + GH + j], o1);
    }
    gemb[g * GE + j] = o0;
    gemb[g * GE + GH + j] = o1;
}

// ---------------- transpose+convert Wf1 [KD][256] f32 -> WT [256][KP] bf16 ----------------
__global__ void k_wt(const float* __restrict__ Wf1, unsigned short* __restrict__ WT) {
    __shared__ float tl[32][33];
    int bk = blockIdx.x & 127;   // 128 k-tiles of 32
    int bn = blockIdx.x >> 7;    // 8 n-tiles of 32
    int tx = threadIdx.x & 31, ty = threadIdx.x >> 5;  // 32 x 8
    int k0 = bk * 32, n0 = bn * 32;
#pragma unroll
    for (int i = 0; i < 4; i++) {
        int k = k0 + ty + i * 8;
        tl[ty + i * 8][tx] = (k < KD) ? Wf1[k * HIDD + n0 + tx] : 0.0f;
    }
    __syncthreads();
#pragma unroll
    for (int i = 0; i < 4; i++) {
        int n = n0 + ty + i * 8;
        WT[n * KP + k0 + tx] = f2bf(tl[tx][ty + i * 8]);
    }
}

// ---------------- build combined [NG][KP] bf16 (zero-padded) ----------------
__global__ void k_comb(const float* __restrict__ gemb, const float* __restrict__ comp,
                       const float* __restrict__ prot, unsigned short* __restrict__ comb) {
    size_t t = (size_t)blockIdx.x * 256 + threadIdx.x;  // NG*KP threads exactly
    int g = (int)(t >> 12), k = (int)(t & (KP - 1));
    float v = 0.0f;
    if (k < GE) v = gemb[g * GE + k];
    else if (k < GE + CDIM) v = comp[(size_t)g * CDIM + (k - GE)];
    else if (k < KD) v = prot[g * PDIM + (k - GE - CDIM)];
    comb[t] = f2bf(v);
}

// ---------------- MFMA head GEMM: out = sigmoid(relu(comb@Wf1+bf1)@Wf2+bf2) ----------------
// C^T orientation: A = WT rows (n), B = comb rows (g). Block: 32 graphs x all 256 n.
__global__ __launch_bounds__(256) void k_gemm_mfma(
        const unsigned short* __restrict__ WT, const unsigned short* __restrict__ comb,
        const float* __restrict__ bf1, const float* __restrict__ Wf2,
        const float* __restrict__ bf2, float* __restrict__ out) {
    __shared__ float red[32];
    int t = threadIdx.x;
    int wv = t >> 6, lane = t & 63;
    int lg = lane >> 4, lr = lane & 15;
    int g0 = blockIdx.x * 32;

    const unsigned short* wbase = WT + (size_t)(wv * 64 + lr) * KP + lg * 8;
    const unsigned short* cbase = comb + (size_t)(g0 + lr) * KP + lg * 8;

    f32x4 acc[4][2];
#pragma unroll
    for (int i = 0; i < 4; i++)
#pragma unroll
        for (int j = 0; j < 2; j++) acc[i][j] = (f32x4){0.f, 0.f, 0.f, 0.f};

    bf16x8 a[4], b[2], an[4], bn[2];
#pragma unroll
    for (int nt = 0; nt < 4; nt++) a[nt] = *reinterpret_cast<const bf16x8*>(wbase + nt * 16 * KP);
#pragma unroll
    for (int gt = 0; gt < 2; gt++) b[gt] = *reinterpret_cast<const bf16x8*>(cbase + gt * 16 * KP);

#pragma unroll 1
    for (int k = 32; k <= KLOOP; k += 32) {
        if (k < KLOOP) {
#pragma unroll
            for (int nt = 0; nt < 4; nt++)
                an[nt] = *reinterpret_cast<const bf16x8*>(wbase + nt * 16 * KP + k);
#pragma unroll
            for (int gt = 0; gt < 2; gt++)
                bn[gt] = *reinterpret_cast<const bf16x8*>(cbase + gt * 16 * KP + k);
        }
#pragma unroll
        for (int nt = 0; nt < 4; nt++)
#pragma unroll
            for (int gt = 0; gt < 2; gt++)
                acc[nt][gt] = __builtin_amdgcn_mfma_f32_16x16x32_bf16(a[nt], b[gt], acc[nt][gt], 0, 0, 0);
#pragma unroll
        for (int nt = 0; nt < 4; nt++) a[nt] = an[nt];
#pragma unroll
        for (int gt = 0; gt < 2; gt++) b[gt] = bn[gt];
    }

    if (t < 32) red[t] = 0.0f;
    __syncthreads();
    float bf2c = bf2[0];
#pragma unroll
    for (int gt = 0; gt < 2; gt++) {
        float pv = 0.0f;
#pragma unroll
        for (int nt = 0; nt < 4; nt++) {
            int nb = wv * 64 + nt * 16 + lg * 4;
#pragma unroll
            for (int r = 0; r < 4; r++) {
                float h = fmaxf(acc[nt][gt][r] + bf1[nb + r], 0.0f);
                pv = fmaf(h, Wf2[nb + r], pv);
            }
        }
        pv += __shfl_xor(pv, 16);
        pv += __shfl_xor(pv, 32);
        if (lane < 16) atomicAdd(&red[gt * 16 + lane], pv);
    }
    __syncthreads();
    if (t < 32) out[g0 + t] = 1.0f / (1.0f + expf(-(red[t] + bf2c)));
}

extern "C" void kernel_launch(void* const* d_in, const int* in_sizes, int n_in,
                              void* d_out, int out_size, void* d_ws, size_t ws_size,
                              hipStream_t stream) {
    const float* node_x = (const float*)d_in[0];
    const float* comp   = (const float*)d_in[1];
    const float* prot   = (const float*)d_in[2];
    const int*   ei     = (const int*)d_in[3];
    const int*   batch  = (const int*)d_in[4];
    const float* W1  = (const float*)d_in[5];
    const float* b1  = (const float*)d_in[6];
    const float* W2  = (const float*)d_in[7];
    const float* b2  = (const float*)d_in[8];
    const float* Wg  = (const float*)d_in[9];
    const float* bg  = (const float*)d_in[10];
    const float* Wf1 = (const float*)d_in[11];
    const float* bf1 = (const float*)d_in[12];
    const float* Wf2 = (const float*)d_in[13];
    const float* bf2 = (const float*)d_in[14];
    float* out = (float*)d_out;

    float* w    = (float*)d_ws;
    float* deg  = w;                         // NN floats (dinv in place; later WT overlays)
    float* s    = deg + NN;                  // NN
    float* agg2 = s + NN;                    // NN*64 (134 MB; later comb overlays)
    float* sums = agg2 + (size_t)NN * GH;    // NG*64
    float* cnt  = sums + NG * GH;            // NG
    float* gemb = cnt + NG;                  // NG*128

    // exact-size overlays of dead buffers (zero net ws growth):
    unsigned short* WT   = (unsigned short*)deg;   // 256*4096*2  == NN*4 bytes
    unsigned short* comb = (unsigned short*)agg2;  // NG*4096*2   == NN*64*4 bytes

    k_init<<<(NG * GH + 255) / 256, 256, 0, stream>>>(deg, sums, cnt);
    k_deg<<<NE / 256, 256, 0, stream>>>(ei, deg);
    k_dinv_s<<<NN / 256, 256, 0, stream>>>(node_x, deg, s);
    k_s<<<NE / 256, 256, 0, stream>>>(ei, node_x, deg, s);
    k_agg_init<<<(NN * GH) / 256, 256, 0, stream>>>(s, deg, W1, b1, agg2);
    k_edge_scatter<<<(NE * GH) / 256, 256, 0, stream>>>(ei, s, deg, W1, b1, agg2);
    k_node<<<(NN * GH) / 256, 256, 0, stream>>>(agg2, W2, b2, batch, sums, cnt);
    k_graph<<<(NG * GH) / 256, 256, 0, stream>>>(sums, cnt, Wg, bg, gemb);
    k_wt<<<1024, 256, 0, stream>>>(Wf1, WT);               // deg/dinv dead from here
    k_comb<<<(NG * KP) / 256, 256, 0, stream>>>(gemb, comp, prot, comb);  // agg2 dead
    k_gemm_mfma<<<NG / 32, 256, 0, stream>>>(WT, comb, bf1, Wf2, bf2, out);
}

// Round 3
// 1108.628 us; speedup vs baseline: 2.2484x; 1.2922x over previous
//
#include <hip/hip_runtime.h>

#define NN 524288
#define NE 2097152
#define NG 16384
#define CDIM 3539
#define PDIM 384
#define GH 64
#define GE 128
#define HIDD 256
#define KD (GE + CDIM + PDIM)  // 4051
#define KP 4096                // padded K stride (bf16 elems)
#define KLOOP 4064             // 127*32 >= KD, multiple of 32

typedef short bf16x8 __attribute__((ext_vector_type(8)));
typedef unsigned short u16x8 __attribute__((ext_vector_type(8)));
typedef float f32x4 __attribute__((ext_vector_type(4)));

__device__ inline unsigned short f2bf(float f) {
    unsigned int u = __float_as_uint(f);
    u += 0x7FFF + ((u >> 16) & 1);  // RNE
    return (unsigned short)(u >> 16);
}

// ---------------- init: deg=1 (self-loop), cursor=0, zero pooling buffers ----------------
__global__ void k_init(float* __restrict__ deg, int* __restrict__ cursor,
                       float* __restrict__ sums, float* __restrict__ cnt) {
    int i = blockIdx.x * blockDim.x + threadIdx.x;
    if (i < NN) { deg[i] = 1.0f; cursor[i] = 0; }
    if (i < NG * GH) sums[i] = 0.0f;
    if (i < NG) cnt[i] = 0.0f;
}

// ---------------- in-degree histogram over col ----------------
__global__ void k_deg(const int* __restrict__ ei, float* __restrict__ deg) {
    int e = blockIdx.x * blockDim.x + threadIdx.x;
    if (e < NE) atomicAdd(&deg[ei[NE + e]], 1.0f);
}

// ---------------- dinv, f2a = {dinv*x, dinv}, integer edge counts ----------------
__global__ void k_prep(const float* __restrict__ node_x, const float* __restrict__ deg,
                       float2* __restrict__ f2a, int* __restrict__ ecnt) {
    int n = blockIdx.x * blockDim.x + threadIdx.x;
    float d = deg[n];
    float di = rsqrtf(d);
    f2a[n] = make_float2(di * node_x[n], di);
    ecnt[n] = (int)(d - 0.5f);  // d = count + 1.0 exactly (counts < 2^24)
}

// ---------------- 3-kernel exclusive scan of ecnt[NN] -> offs[NN+1] ----------------
__global__ void k_scan1(const int* __restrict__ ecnt, int* __restrict__ bsum) {
    __shared__ int ls[256];
    int t = threadIdx.x;
    ls[t] = ecnt[blockIdx.x * 256 + t];
    __syncthreads();
    for (int d = 128; d > 0; d >>= 1) { if (t < d) ls[t] += ls[t + d]; __syncthreads(); }
    if (t == 0) bsum[blockIdx.x] = ls[0];
}

__global__ void k_scan2(int* __restrict__ bsum) {  // 1 block, 2048 elems
    __shared__ int ls[256];
    int t = threadIdx.x;
    int loc[8]; int s = 0;
#pragma unroll
    for (int i = 0; i < 8; i++) { loc[i] = bsum[t * 8 + i]; s += loc[i]; }
    ls[t] = s; __syncthreads();
    for (int d = 1; d < 256; d <<= 1) {
        int add = (t >= d) ? ls[t - d] : 0; __syncthreads();
        ls[t] += add; __syncthreads();
    }
    int run = ls[t] - s;  // exclusive
#pragma unroll
    for (int i = 0; i < 8; i++) { int tmp = loc[i]; bsum[t * 8 + i] = run; run += tmp; }
}

__global__ void k_scan3(const int* __restrict__ ecnt, const int* __restrict__ bsum,
                        int* __restrict__ offs) {
    __shared__ int ls[256];
    int t = threadIdx.x, n = blockIdx.x * 256 + t;
    int v = ecnt[n];
    ls[t] = v; __syncthreads();
    for (int d = 1; d < 256; d <<= 1) {
        int add = (t >= d) ? ls[t - d] : 0; __syncthreads();
        ls[t] += add; __syncthreads();
    }
    offs[n] = bsum[blockIdx.x] + ls[t] - v;
    if (n == 0) offs[NN] = NE;
}

// ---------------- CSR fill (row indices bucketed by destination col) ----------------
__global__ void k_fill(const int* __restrict__ ei, const int* __restrict__ offs,
                       int* __restrict__ cursor, int* __restrict__ csr) {
    int e = blockIdx.x * 256 + threadIdx.x;
    int r = ei[e], c = ei[NE + e];
    int p = atomicAdd(&cursor[c], 1);
    csr[offs[c] + p] = r;
}

// ---------------- pass A: s[c] = dinv_c * (sum_r dinv_r x_r + dinv_c x_c); sd={s,dinv} ----------------
__global__ void k_sg(const int* __restrict__ offs, const int* __restrict__ csr,
                     const float2* __restrict__ f2a, float2* __restrict__ sd) {
    int n = blockIdx.x * 256 + threadIdx.x;
    int a = offs[n], b = offs[n + 1];
    float2 me = f2a[n];
    float sum = me.x;  // self-loop term dinv_c * x_c
    for (int e = a; e < b; ++e) sum += f2a[csr[e]].x;
    sd[n] = make_float2(me.y * sum, me.y);
}

// ---------------- pass B fused: gather agg -> x2 = relu(agg@W2+b2) -> pool ----------------
__global__ __launch_bounds__(256) void k_nodefused(
        const int* __restrict__ offs, const int* __restrict__ csr,
        const float2* __restrict__ sd, const float* __restrict__ W1,
        const float* __restrict__ b1, const float* __restrict__ W2,
        const float* __restrict__ b2, const int* __restrict__ batch,
        float* __restrict__ sums, float* __restrict__ cnt) {
    __shared__ float w2s[GH * GH];   // 16 KB
    __shared__ float aggL[4][GH];
    int t = threadIdx.x;
    for (int i = t; i < GH * GH; i += 256) w2s[i] = W2[i];
    int wv = t >> 6, j = t & 63;
    int n = blockIdx.x * 4 + wv;
    float w1j = W1[j], b1j = b1[j];
    int a = offs[n], bnd = offs[n + 1];
    float2 sdn = sd[n];
    float x1 = fmaxf(fmaf(sdn.x, w1j, b1j), 0.0f);
    float acc = sdn.y * x1;          // self-loop: dinv_c * x1_c (outer dinv_c applied below)
    for (int e = a; e < bnd; ++e) {
        int r = csr[e];
        float2 v = sd[r];
        float xr = fmaxf(fmaf(v.x, w1j, b1j), 0.0f);
        acc = fmaf(v.y, xr, acc);
    }
    aggL[wv][j] = sdn.y * acc;
    __syncthreads();
    float acc2 = b2[j];
#pragma unroll
    for (int k = 0; k < GH; ++k) acc2 = fmaf(aggL[wv][k], w2s[k * GH + j], acc2);
    float x2 = fmaxf(acc2, 0.0f);
    int g = batch[n];
    atomicAdd(&sums[g * GH + j], x2);
    if (j == 0) atomicAdd(&cnt[g], 1.0f);
}

// ---------------- per-graph: pooled = sums/cnt; gemb = pooled @ Wg + bg ----------------
__global__ void k_graph(const float* __restrict__ sums, const float* __restrict__ cnt,
                        const float* __restrict__ Wg, const float* __restrict__ bg,
                        float* __restrict__ gemb) {
    __shared__ float wgs[GH * GE];   // 32 KB
    __shared__ float ps[4 * GH];
    int t = threadIdx.x;
    for (int i = t; i < GH * GE; i += 256) wgs[i] = Wg[i];
    int gid = blockIdx.x * 256 + t;  // NG*64 threads exactly
    int g = gid >> 6, j = t & 63, w = t >> 6;
    float c = fmaxf(cnt[g], 1.0f);
    ps[t] = sums[g * GH + j] / c;
    __syncthreads();
    float o0 = bg[j], o1 = bg[GH + j];
#pragma unroll
    for (int k = 0; k < GH; k++) {
        float p = ps[w * GH + k];
        o0 = fmaf(p, wgs[k * GE + j], o0);
        o1 = fmaf(p, wgs[k * GE + GH + j], o1);
    }
    gemb[g * GE + j] = o0;
    gemb[g * GE + GH + j] = o1;
}

// ---------------- transpose+convert Wf1 [KD][256] f32 -> WT [256][KP] bf16 ----------------
__global__ void k_wt(const float* __restrict__ Wf1, unsigned short* __restrict__ WT) {
    __shared__ float tl[32][33];
    int bk = blockIdx.x & 127;
    int bn = blockIdx.x >> 7;
    int tx = threadIdx.x & 31, ty = threadIdx.x >> 5;  // 32 x 8
    int k0 = bk * 32, n0 = bn * 32;
#pragma unroll
    for (int i = 0; i < 4; i++) {
        int k = k0 + ty + i * 8;
        tl[ty + i * 8][tx] = (k < KD) ? Wf1[k * HIDD + n0 + tx] : 0.0f;
    }
    __syncthreads();
#pragma unroll
    for (int i = 0; i < 4; i++) {
        int n = n0 + ty + i * 8;
        WT[n * KP + k0 + tx] = f2bf(tl[tx][ty + i * 8]);
    }
}

// ---------------- build combined [NG][KP] bf16 (zero-padded), 8 elems/thread ----------------
__global__ void k_comb(const float* __restrict__ gemb, const float* __restrict__ comp,
                       const float* __restrict__ prot, unsigned short* __restrict__ comb) {
    size_t t = ((size_t)blockIdx.x * 256 + threadIdx.x) * 8;  // NG*KP elems total
    int g = (int)(t >> 12), k0 = (int)(t & (KP - 1));
    u16x8 r;
#pragma unroll
    for (int i = 0; i < 8; i++) {
        int k = k0 + i;
        float v = 0.0f;
        if (k < GE) v = gemb[g * GE + k];
        else if (k < GE + CDIM) v = comp[(size_t)g * CDIM + (k - GE)];
        else if (k < KD) v = prot[g * PDIM + (k - GE - CDIM)];
        r[i] = f2bf(v);
    }
    *reinterpret_cast<u16x8*>(comb + t) = r;
}

// ---------------- MFMA head GEMM: out = sigmoid(relu(comb@Wf1+bf1)@Wf2+bf2) ----------------
__global__ __launch_bounds__(256) void k_gemm_mfma(
        const unsigned short* __restrict__ WT, const unsigned short* __restrict__ comb,
        const float* __restrict__ bf1, const float* __restrict__ Wf2,
        const float* __restrict__ bf2, float* __restrict__ out) {
    __shared__ float red[32];
    int t = threadIdx.x;
    int wv = t >> 6, lane = t & 63;
    int lg = lane >> 4, lr = lane & 15;
    int g0 = blockIdx.x * 32;

    const unsigned short* wbase = WT + (size_t)(wv * 64 + lr) * KP + lg * 8;
    const unsigned short* cbase = comb + (size_t)(g0 + lr) * KP + lg * 8;

    f32x4 acc[4][2];
#pragma unroll
    for (int i = 0; i < 4; i++)
#pragma unroll
        for (int j = 0; j < 2; j++) acc[i][j] = (f32x4){0.f, 0.f, 0.f, 0.f};

    bf16x8 a[4], b[2], an[4], bn[2];
#pragma unroll
    for (int nt = 0; nt < 4; nt++) a[nt] = *reinterpret_cast<const bf16x8*>(wbase + nt * 16 * KP);
#pragma unroll
    for (int gt = 0; gt < 2; gt++) b[gt] = *reinterpret_cast<const bf16x8*>(cbase + gt * 16 * KP);

#pragma unroll 1
    for (int k = 32; k <= KLOOP; k += 32) {
        if (k < KLOOP) {
#pragma unroll
            for (int nt = 0; nt < 4; nt++)
                an[nt] = *reinterpret_cast<const bf16x8*>(wbase + nt * 16 * KP + k);
#pragma unroll
            for (int gt = 0; gt < 2; gt++)
                bn[gt] = *reinterpret_cast<const bf16x8*>(cbase + gt * 16 * KP + k);
        }
#pragma unroll
        for (int nt = 0; nt < 4; nt++)
#pragma unroll
            for (int gt = 0; gt < 2; gt++)
                acc[nt][gt] = __builtin_amdgcn_mfma_f32_16x16x32_bf16(a[nt], b[gt], acc[nt][gt], 0, 0, 0);
#pragma unroll
        for (int nt = 0; nt < 4; nt++) a[nt] = an[nt];
#pragma unroll
        for (int gt = 0; gt < 2; gt++) b[gt] = bn[gt];
    }

    if (t < 32) red[t] = 0.0f;
    __syncthreads();
    float bf2c = bf2[0];
#pragma unroll
    for (int gt = 0; gt < 2; gt++) {
        float pv = 0.0f;
#pragma unroll
        for (int nt = 0; nt < 4; nt++) {
            int nb = wv * 64 + nt * 16 + lg * 4;
#pragma unroll
            for (int r = 0; r < 4; r++) {
                float h = fmaxf(acc[nt][gt][r] + bf1[nb + r], 0.0f);
                pv = fmaf(h, Wf2[nb + r], pv);
            }
        }
        pv += __shfl_xor(pv, 16);
        pv += __shfl_xor(pv, 32);
        if (lane < 16) atomicAdd(&red[gt * 16 + lane], pv);
    }
    __syncthreads();
    if (t < 32) out[g0 + t] = 1.0f / (1.0f + expf(-(red[t] + bf2c)));
}

extern "C" void kernel_launch(void* const* d_in, const int* in_sizes, int n_in,
                              void* d_out, int out_size, void* d_ws, size_t ws_size,
                              hipStream_t stream) {
    const float* node_x = (const float*)d_in[0];
    const float* comp   = (const float*)d_in[1];
    const float* prot   = (const float*)d_in[2];
    const int*   ei     = (const int*)d_in[3];
    const int*   batch  = (const int*)d_in[4];
    const float* W1  = (const float*)d_in[5];
    const float* b1  = (const float*)d_in[6];
    const float* W2  = (const float*)d_in[7];
    const float* b2  = (const float*)d_in[8];
    const float* Wg  = (const float*)d_in[9];
    const float* bg  = (const float*)d_in[10];
    const float* Wf1 = (const float*)d_in[11];
    const float* bf1 = (const float*)d_in[12];
    const float* Wf2 = (const float*)d_in[13];
    const float* bf2 = (const float*)d_in[14];
    float* out = (float*)d_out;

    // -------- workspace layout (138.0 MiB total; all offsets 256B-aligned) --------
    // Region A [0, 134217728): comb (bf16). Transient overlays (dead before k_comb):
    char* W = (char*)d_ws;
    unsigned short* comb = (unsigned short*)W;
    float*  deg    = (float*)(W + 0);          // NN f32
    float2* f2a    = (float2*)(W + 2097152);   // NN float2
    float2* sd     = (float2*)(W + 6291456);   // NN float2
    int*    ecnt   = (int*)(W + 10485760);     // NN int
    int*    offs   = (int*)(W + 12582912);     // NN+1 int
    int*    cursor = (int*)(W + 14680320);     // NN int
    int*    bsum   = (int*)(W + 16777728);     // 2048 int
    int*    csr    = (int*)(W + 16786432);     // NE int
    float*  sums   = (float*)(W + 25175040);   // NG*64 f32
    float*  cnt    = (float*)(W + 29369344);   // NG f32
    // Region B/C (live to the end):
    float*  gemb   = (float*)(W + 134217728);          // NG*128 f32
    unsigned short* WT = (unsigned short*)(W + 142606336);  // 256*KP bf16

    k_init<<<4096, 256, 0, stream>>>(deg, cursor, sums, cnt);
    k_deg<<<NE / 256, 256, 0, stream>>>(ei, deg);
    k_prep<<<NN / 256, 256, 0, stream>>>(node_x, deg, f2a, ecnt);
    k_scan1<<<NN / 256, 256, 0, stream>>>(ecnt, bsum);
    k_scan2<<<1, 256, 0, stream>>>(bsum);
    k_scan3<<<NN / 256, 256, 0, stream>>>(ecnt, bsum, offs);
    k_fill<<<NE / 256, 256, 0, stream>>>(ei, offs, cursor, csr);
    k_sg<<<NN / 256, 256, 0, stream>>>(offs, csr, f2a, sd);
    k_nodefused<<<NN / 4, 256, 0, stream>>>(offs, csr, sd, W1, b1, W2, b2, batch, sums, cnt);
    k_graph<<<NG * GH / 256, 256, 0, stream>>>(sums, cnt, Wg, bg, gemb);
    k_wt<<<1024, 256, 0, stream>>>(Wf1, WT);
    k_comb<<<NG * KP / (256 * 8), 256, 0, stream>>>(gemb, comp, prot, comb);
    k_gemm_mfma<<<NG / 32, 256, 0, stream>>>(WT, comb, bf1, Wf2, bf2, out);
}

// Round 4
// 1029.718 us; speedup vs baseline: 2.4207x; 1.0766x over previous
//
#include <hip/hip_runtime.h>

#define NN 524288
#define NE 2097152
#define NG 16384
#define CDIM 3539
#define PDIM 384
#define GH 64
#define GE 128
#define HIDD 256
#define KD (GE + CDIM + PDIM)  // 4051
#define KP 4096                // padded K stride (bf16 elems)
#define KLOOP 4064             // 127*32 >= KD, multiple of 32

typedef short bf16x8 __attribute__((ext_vector_type(8)));
typedef unsigned short u16x8 __attribute__((ext_vector_type(8)));
typedef float f32x4 __attribute__((ext_vector_type(4)));

__device__ inline unsigned short f2bf(float f) {
    unsigned int u = __float_as_uint(f);
    u += 0x7FFF + ((u >> 16) & 1);  // RNE
    return (unsigned short)(u >> 16);
}

// ---------------- init: deg=1 (self-loop), cursor=0, zero pooling buffers ----------------
__global__ void k_init(float* __restrict__ deg, int* __restrict__ cursor,
                       float* __restrict__ sums, float* __restrict__ cnt) {
    int i = blockIdx.x * blockDim.x + threadIdx.x;
    if (i < NN) { deg[i] = 1.0f; cursor[i] = 0; }
    if (i < NG * GH) sums[i] = 0.0f;
    if (i < NG) cnt[i] = 0.0f;
}

// ---------------- in-degree histogram over col ----------------
__global__ void k_deg(const int* __restrict__ ei, float* __restrict__ deg) {
    int e = blockIdx.x * blockDim.x + threadIdx.x;
    if (e < NE) atomicAdd(&deg[ei[NE + e]], 1.0f);
}

// ---------------- dinv, f2a = {dinv*x, dinv}, integer edge counts ----------------
__global__ void k_prep(const float* __restrict__ node_x, const float* __restrict__ deg,
                       float2* __restrict__ f2a, int* __restrict__ ecnt) {
    int n = blockIdx.x * blockDim.x + threadIdx.x;
    float d = deg[n];
    float di = rsqrtf(d);
    f2a[n] = make_float2(di * node_x[n], di);
    ecnt[n] = (int)(d - 0.5f);  // d = count + 1.0 exactly
}

// ---------------- 3-kernel exclusive scan of ecnt[NN] -> offs[NN+1] ----------------
__global__ void k_scan1(const int* __restrict__ ecnt, int* __restrict__ bsum) {
    __shared__ int ls[256];
    int t = threadIdx.x;
    ls[t] = ecnt[blockIdx.x * 256 + t];
    __syncthreads();
    for (int d = 128; d > 0; d >>= 1) { if (t < d) ls[t] += ls[t + d]; __syncthreads(); }
    if (t == 0) bsum[blockIdx.x] = ls[0];
}

__global__ void k_scan2(int* __restrict__ bsum) {  // 1 block, 2048 elems
    __shared__ int ls[256];
    int t = threadIdx.x;
    int loc[8]; int s = 0;
#pragma unroll
    for (int i = 0; i < 8; i++) { loc[i] = bsum[t * 8 + i]; s += loc[i]; }
    ls[t] = s; __syncthreads();
    for (int d = 1; d < 256; d <<= 1) {
        int add = (t >= d) ? ls[t - d] : 0; __syncthreads();
        ls[t] += add; __syncthreads();
    }
    int run = ls[t] - s;  // exclusive
#pragma unroll
    for (int i = 0; i < 8; i++) { int tmp = loc[i]; bsum[t * 8 + i] = run; run += tmp; }
}

__global__ void k_scan3(const int* __restrict__ ecnt, const int* __restrict__ bsum,
                        int* __restrict__ offs) {
    __shared__ int ls[256];
    int t = threadIdx.x, n = blockIdx.x * 256 + t;
    int v = ecnt[n];
    ls[t] = v; __syncthreads();
    for (int d = 1; d < 256; d <<= 1) {
        int add = (t >= d) ? ls[t - d] : 0; __syncthreads();
        ls[t] += add; __syncthreads();
    }
    offs[n] = bsum[blockIdx.x] + ls[t] - v;
    if (n == 0) offs[NN] = NE;
}

// ---------------- CSR fill (row indices bucketed by destination col) ----------------
__global__ void k_fill(const int* __restrict__ ei, const int* __restrict__ offs,
                       int* __restrict__ cursor, int* __restrict__ csr) {
    int e = blockIdx.x * 256 + threadIdx.x;
    int r = ei[e], c = ei[NE + e];
    int p = atomicAdd(&cursor[c], 1);
    csr[offs[c] + p] = r;
}

// ---------------- materialize pre_val[e] = dinv_r * x_r (thread-parallel random gather) ----
__global__ void k_preval(const int* __restrict__ csr, const float2* __restrict__ f2a,
                         float* __restrict__ pre_val) {
    int e = blockIdx.x * 256 + threadIdx.x;
    pre_val[e] = f2a[csr[e]].x;
}

// ---------------- pass A: s[c] = dinv_c*(sum pre_val + dinv_c x_c); sd={s,dinv} ----------
__global__ void k_sg(const int* __restrict__ offs, const float* __restrict__ pre_val,
                     const float2* __restrict__ f2a, float2* __restrict__ sd) {
    int n = blockIdx.x * 256 + threadIdx.x;
    int a = offs[n], b = offs[n + 1];
    float2 me = f2a[n];
    float sum = me.x;
    for (int e = a; e < b; ++e) sum += pre_val[e];
    sd[n] = make_float2(me.y * sum, me.y);
}

// ---------------- materialize val[e] = sd[csr[e]] (thread-parallel random gather) --------
__global__ void k_val(const int* __restrict__ csr, const float2* __restrict__ sd,
                      float2* __restrict__ val) {
    int e = blockIdx.x * 256 + threadIdx.x;
    val[e] = sd[csr[e]];
}

// ---------------- gather: aggB[n][j] = bf16( dinv_n*(self + sum_e dinv_r x1_r) ) ---------
__global__ __launch_bounds__(256) void k_gather(
        const int* __restrict__ offs, const float2* __restrict__ val,
        const float2* __restrict__ sd, const float* __restrict__ W1,
        const float* __restrict__ b1, const int* __restrict__ batch,
        unsigned short* __restrict__ aggB, float* __restrict__ cnt) {
    int t = threadIdx.x;
    int wv = t >> 6, j = t & 63;
    int n = blockIdx.x * 4 + wv;
    float w1j = W1[j], b1j = b1[j];
    int a = offs[n], bnd = offs[n + 1];
    float2 sdn = sd[n];
    float x1 = fmaxf(fmaf(sdn.x, w1j, b1j), 0.0f);
    float acc = sdn.y * x1;  // self-loop term
    for (int e = a; e < bnd; ++e) {
        float2 v = val[e];   // contiguous stream, wave-uniform
        float xr = fmaxf(fmaf(v.x, w1j, b1j), 0.0f);
        acc = fmaf(v.y, xr, acc);
    }
    aggB[(size_t)n * GH + j] = f2bf(sdn.y * acc);
    if (j == 0) atomicAdd(&cnt[batch[n]], 1.0f);
}

// ---------------- MFMA: x2 = relu(aggB @ W2 + b2); pool into sums ----------------
__global__ __launch_bounds__(256) void k_x2pool(
        const unsigned short* __restrict__ aggB, const unsigned short* __restrict__ W2T,
        const float* __restrict__ b2, const int* __restrict__ batch,
        float* __restrict__ sums) {
    int t = threadIdx.x;
    int wv = t >> 6, lane = t & 63;
    int lg = lane >> 4, lr = lane & 15;
    int n0 = blockIdx.x * 64 + wv * 16;

    bf16x8 a0 = *reinterpret_cast<const bf16x8*>(aggB + (size_t)(n0 + lr) * GH + lg * 8);
    bf16x8 a1 = *reinterpret_cast<const bf16x8*>(aggB + (size_t)(n0 + lr) * GH + 32 + lg * 8);

    f32x4 acc[4];
#pragma unroll
    for (int jt = 0; jt < 4; jt++) acc[jt] = (f32x4){0.f, 0.f, 0.f, 0.f};
#pragma unroll
    for (int jt = 0; jt < 4; jt++) {
        bf16x8 b0 = *reinterpret_cast<const bf16x8*>(W2T + (jt * 16 + lr) * GH + lg * 8);
        bf16x8 b1 = *reinterpret_cast<const bf16x8*>(W2T + (jt * 16 + lr) * GH + 32 + lg * 8);
        acc[jt] = __builtin_amdgcn_mfma_f32_16x16x32_bf16(a0, b0, acc[jt], 0, 0, 0);
        acc[jt] = __builtin_amdgcn_mfma_f32_16x16x32_bf16(a1, b1, acc[jt], 0, 0, 0);
    }

    int g0 = batch[n0];
    if (g0 == batch[n0 + 15]) {  // whole 16-node tile in one graph: reduce, 1/16 atomics
#pragma unroll
        for (int jt = 0; jt < 4; jt++) {
            float v = 0.0f;
            float bj = b2[jt * 16 + lr];
#pragma unroll
            for (int r = 0; r < 4; r++) v += fmaxf(acc[jt][r] + bj, 0.0f);
            v += __shfl_xor(v, 16);
            v += __shfl_xor(v, 32);
            if (lane < 16) atomicAdd(&sums[g0 * GH + jt * 16 + lr], v);
        }
    } else {
#pragma unroll
        for (int jt = 0; jt < 4; jt++) {
            float bj = b2[jt * 16 + lr];
#pragma unroll
            for (int r = 0; r < 4; r++) {
                int node = n0 + lg * 4 + r;
                int g = batch[node];
                atomicAdd(&sums[g * GH + jt * 16 + lr], fmaxf(acc[jt][r] + bj, 0.0f));
            }
        }
    }
}

// ---------------- per-graph: pooled = sums/cnt; gemb = pooled @ Wg + bg ----------------
__global__ void k_graph(const float* __restrict__ sums, const float* __restrict__ cnt,
                        const float* __restrict__ Wg, const float* __restrict__ bg,
                        float* __restrict__ gemb) {
    __shared__ float wgs[GH * GE];   // 32 KB
    __shared__ float ps[4 * GH];
    int t = threadIdx.x;
    for (int i = t; i < GH * GE; i += 256) wgs[i] = Wg[i];
    int gid = blockIdx.x * 256 + t;
    int g = gid >> 6, j = t & 63, w = t >> 6;
    float c = fmaxf(cnt[g], 1.0f);
    ps[t] = sums[g * GH + j] / c;
    __syncthreads();
    float o0 = bg[j], o1 = bg[GH + j];
#pragma unroll
    for (int k = 0; k < GH; k++) {
        float p = ps[w * GH + k];
        o0 = fmaf(p, wgs[k * GE + j], o0);
        o1 = fmaf(p, wgs[k * GE + GH + j], o1);
    }
    gemb[g * GE + j] = o0;
    gemb[g * GE + GH + j] = o1;
}

// ---------------- transpose+convert Wf1 -> WT bf16; block 1024 builds W2T ----------------
__global__ void k_wt(const float* __restrict__ Wf1, unsigned short* __restrict__ WT,
                     const float* __restrict__ W2, unsigned short* __restrict__ W2T) {
    if (blockIdx.x == 1024) {  // W2T[j][k] = bf16(W2[k][j]), 64x64
        int t = threadIdx.x;
        for (int i = 0; i < 16; i++) {
            int idx = t * 16 + i;
            int j = idx >> 6, k = idx & 63;
            W2T[j * GH + k] = f2bf(W2[k * GH + j]);
        }
        return;
    }
    __shared__ float tl[32][33];
    int bk = blockIdx.x & 127;
    int bn = blockIdx.x >> 7;
    int tx = threadIdx.x & 31, ty = threadIdx.x >> 5;  // 32 x 8
    int k0 = bk * 32, n0 = bn * 32;
#pragma unroll
    for (int i = 0; i < 4; i++) {
        int k = k0 + ty + i * 8;
        tl[ty + i * 8][tx] = (k < KD) ? Wf1[k * HIDD + n0 + tx] : 0.0f;
    }
    __syncthreads();
#pragma unroll
    for (int i = 0; i < 4; i++) {
        int n = n0 + ty + i * 8;
        WT[n * KP + k0 + tx] = f2bf(tl[tx][ty + i * 8]);
    }
}

// ---------------- build combined [NG][KP] bf16 (zero-padded), 8 elems/thread ----------------
__global__ void k_comb(const float* __restrict__ gemb, const float* __restrict__ comp,
                       const float* __restrict__ prot, unsigned short* __restrict__ comb) {
    size_t t = ((size_t)blockIdx.x * 256 + threadIdx.x) * 8;
    int g = (int)(t >> 12), k0 = (int)(t & (KP - 1));
    u16x8 r;
#pragma unroll
    for (int i = 0; i < 8; i++) {
        int k = k0 + i;
        float v = 0.0f;
        if (k < GE) v = gemb[g * GE + k];
        else if (k < GE + CDIM) v = comp[(size_t)g * CDIM + (k - GE)];
        else if (k < KD) v = prot[g * PDIM + (k - GE - CDIM)];
        r[i] = f2bf(v);
    }
    *reinterpret_cast<u16x8*>(comb + t) = r;
}

// ---------------- MFMA head GEMM: out = sigmoid(relu(comb@Wf1+bf1)@Wf2+bf2) ----------------
__global__ __launch_bounds__(256) void k_gemm_mfma(
        const unsigned short* __restrict__ WT, const unsigned short* __restrict__ comb,
        const float* __restrict__ bf1, const float* __restrict__ Wf2,
        const float* __restrict__ bf2, float* __restrict__ out) {
    __shared__ float red[32];
    int t = threadIdx.x;
    int wv = t >> 6, lane = t & 63;
    int lg = lane >> 4, lr = lane & 15;
    int g0 = blockIdx.x * 32;

    const unsigned short* wbase = WT + (size_t)(wv * 64 + lr) * KP + lg * 8;
    const unsigned short* cbase = comb + (size_t)(g0 + lr) * KP + lg * 8;

    f32x4 acc[4][2];
#pragma unroll
    for (int i = 0; i < 4; i++)
#pragma unroll
        for (int j = 0; j < 2; j++) acc[i][j] = (f32x4){0.f, 0.f, 0.f, 0.f};

    bf16x8 a[4], b[2], an[4], bn[2];
#pragma unroll
    for (int nt = 0; nt < 4; nt++) a[nt] = *reinterpret_cast<const bf16x8*>(wbase + nt * 16 * KP);
#pragma unroll
    for (int gt = 0; gt < 2; gt++) b[gt] = *reinterpret_cast<const bf16x8*>(cbase + gt * 16 * KP);

#pragma unroll 1
    for (int k = 32; k <= KLOOP; k += 32) {
        if (k < KLOOP) {
#pragma unroll
            for (int nt = 0; nt < 4; nt++)
                an[nt] = *reinterpret_cast<const bf16x8*>(wbase + nt * 16 * KP + k);
#pragma unroll
            for (int gt = 0; gt < 2; gt++)
                bn[gt] = *reinterpret_cast<const bf16x8*>(cbase + gt * 16 * KP + k);
        }
#pragma unroll
        for (int nt = 0; nt < 4; nt++)
#pragma unroll
            for (int gt = 0; gt < 2; gt++)
                acc[nt][gt] = __builtin_amdgcn_mfma_f32_16x16x32_bf16(a[nt], b[gt], acc[nt][gt], 0, 0, 0);
#pragma unroll
        for (int nt = 0; nt < 4; nt++) a[nt] = an[nt];
#pragma unroll
        for (int gt = 0; gt < 2; gt++) b[gt] = bn[gt];
    }

    if (t < 32) red[t] = 0.0f;
    __syncthreads();
    float bf2c = bf2[0];
#pragma unroll
    for (int gt = 0; gt < 2; gt++) {
        float pv = 0.0f;
#pragma unroll
        for (int nt = 0; nt < 4; nt++) {
            int nb = wv * 64 + nt * 16 + lg * 4;
#pragma unroll
            for (int r = 0; r < 4; r++) {
                float h = fmaxf(acc[nt][gt][r] + bf1[nb + r], 0.0f);
                pv = fmaf(h, Wf2[nb + r], pv);
            }
        }
        pv += __shfl_xor(pv, 16);
        pv += __shfl_xor(pv, 32);
        if (lane < 16) atomicAdd(&red[gt * 16 + lane], pv);
    }
    __syncthreads();
    if (t < 32) out[g0 + t] = 1.0f / (1.0f + expf(-(red[t] + bf2c)));
}

extern "C" void kernel_launch(void* const* d_in, const int* in_sizes, int n_in,
                              void* d_out, int out_size, void* d_ws, size_t ws_size,
                              hipStream_t stream) {
    const float* node_x = (const float*)d_in[0];
    const float* comp   = (const float*)d_in[1];
    const float* prot   = (const float*)d_in[2];
    const int*   ei     = (const int*)d_in[3];
    const int*   batch  = (const int*)d_in[4];
    const float* W1  = (const float*)d_in[5];
    const float* b1  = (const float*)d_in[6];
    const float* W2  = (const float*)d_in[7];
    const float* b2  = (const float*)d_in[8];
    const float* Wg  = (const float*)d_in[9];
    const float* bg  = (const float*)d_in[10];
    const float* Wf1 = (const float*)d_in[11];
    const float* bf1 = (const float*)d_in[12];
    const float* Wf2 = (const float*)d_in[13];
    const float* bf2 = (const float*)d_in[14];
    float* out = (float*)d_out;

    // -------- workspace layout (≈138.0 MiB; region A [0,134MB) becomes comb at k_comb) ----
    char* W = (char*)d_ws;
    unsigned short* comb = (unsigned short*)W;
    float*  deg     = (float*)(W + 0);          // NN f32 (dead after k_prep)
    float2* f2a     = (float2*)(W + 2097152);   // NN float2
    float2* sd      = (float2*)(W + 6291456);   // NN float2
    int*    ecnt    = (int*)(W + 10485760);     // NN int
    int*    offs    = (int*)(W + 12582912);     // NN+1 int
    int*    cursor  = (int*)(W + 14680320);     // NN int
    int*    bsum    = (int*)(W + 16777728);     // 2048 int
    int*    csr     = (int*)(W + 16786432);     // NE int
    float*  sums    = (float*)(W + 25175040);   // NG*64 f32
    float*  cnt     = (float*)(W + 29369344);   // NG f32
    float*  pre_val = (float*)(W + 33554432);   // NE f32
    float2* val     = (float2*)(W + 41943040);  // NE float2
    unsigned short* aggB = (unsigned short*)(W + 58720256);  // NN*64 bf16 (67 MB)
    // Region B/C (live to the end):
    float*  gemb    = (float*)(W + 134217728);              // NG*128 f32
    unsigned short* WT  = (unsigned short*)(W + 142606336); // 256*KP bf16
    unsigned short* W2T = (unsigned short*)(W + 144703488); // 64*64 bf16

    k_init<<<4096, 256, 0, stream>>>(deg, cursor, sums, cnt);
    k_deg<<<NE / 256, 256, 0, stream>>>(ei, deg);
    k_prep<<<NN / 256, 256, 0, stream>>>(node_x, deg, f2a, ecnt);
    k_scan1<<<NN / 256, 256, 0, stream>>>(ecnt, bsum);
    k_scan2<<<1, 256, 0, stream>>>(bsum);
    k_scan3<<<NN / 256, 256, 0, stream>>>(ecnt, bsum, offs);
    k_fill<<<NE / 256, 256, 0, stream>>>(ei, offs, cursor, csr);
    k_preval<<<NE / 256, 256, 0, stream>>>(csr, f2a, pre_val);
    k_sg<<<NN / 256, 256, 0, stream>>>(offs, pre_val, f2a, sd);
    k_val<<<NE / 256, 256, 0, stream>>>(csr, sd, val);
    k_gather<<<NN / 4, 256, 0, stream>>>(offs, val, sd, W1, b1, batch, aggB, cnt);
    k_x2pool<<<NN / 64, 256, 0, stream>>>(aggB, W2T, b2, batch, sums);
    k_graph<<<NG * GH / 256, 256, 0, stream>>>(sums, cnt, Wg, bg, gemb);
    k_wt<<<1025, 256, 0, stream>>>(Wf1, WT, W2, W2T);
    k_comb<<<NG * KP / (256 * 8), 256, 0, stream>>>(gemb, comp, prot, comb);
    k_gemm_mfma<<<NG / 32, 256, 0, stream>>>(WT, comb, bf1, Wf2, bf2, out);
}

// Round 5
// 960.369 us; speedup vs baseline: 2.5955x; 1.0722x over previous
//
#include <hip/hip_runtime.h>

#define NN 524288
#define NE 2097152
#define NG 16384
#define CDIM 3539
#define PDIM 384
#define GH 64
#define GE 128
#define HIDD 256
#define KD (GE + CDIM + PDIM)  // 4051
#define KP 4096                // padded K stride (bf16 elems)
#define KLOOP 4064             // 127*32 >= KD, multiple of 32

typedef short bf16x8 __attribute__((ext_vector_type(8)));
typedef unsigned short u16x8 __attribute__((ext_vector_type(8)));
typedef float f32x4 __attribute__((ext_vector_type(4)));

__device__ inline unsigned short f2bf(float f) {
    unsigned int u = __float_as_uint(f);
    u += 0x7FFF + ((u >> 16) & 1);  // RNE
    return (unsigned short)(u >> 16);
}

// ---------------- init: deg=1 (self-loop), cursor=0, zero sums ----------------
__global__ void k_init(float* __restrict__ deg, int* __restrict__ cursor,
                       float* __restrict__ sums) {
    int i = blockIdx.x * blockDim.x + threadIdx.x;
    if (i < NN) { deg[i] = 1.0f; cursor[i] = 0; }
    if (i < NG * GH) sums[i] = 0.0f;
}

// ---------------- in-degree histogram over col ----------------
__global__ void k_deg(const int* __restrict__ ei, float* __restrict__ deg) {
    int e = blockIdx.x * blockDim.x + threadIdx.x;
    if (e < NE) atomicAdd(&deg[ei[NE + e]], 1.0f);
}

// ---------------- dinv, f2a = {dinv*x, dinv}, integer edge counts ----------------
__global__ void k_prep(const float* __restrict__ node_x, const float* __restrict__ deg,
                       float2* __restrict__ f2a, int* __restrict__ ecnt) {
    int n = blockIdx.x * blockDim.x + threadIdx.x;
    float d = deg[n];
    float di = rsqrtf(d);
    f2a[n] = make_float2(di * node_x[n], di);
    ecnt[n] = (int)(d - 0.5f);  // d = count + 1.0 exactly
}

// ---------------- cnt[g] via binary search on sorted batch ----------------
__global__ void k_cnt(const int* __restrict__ batch, float* __restrict__ cnt) {
    int g = blockIdx.x * 256 + threadIdx.x;  // NG threads
    int lo = 0, hi = NN;
    while (lo < hi) { int mid = (lo + hi) >> 1; if (batch[mid] < g) lo = mid + 1; else hi = mid; }
    int lo2 = lo, hi2 = NN;
    while (lo2 < hi2) { int mid = (lo2 + hi2) >> 1; if (batch[mid] < g + 1) lo2 = mid + 1; else hi2 = mid; }
    cnt[g] = (float)(lo2 - lo);
}

// ---------------- 3-kernel exclusive scan of ecnt[NN] -> offs[NN+1] ----------------
__global__ void k_scan1(const int* __restrict__ ecnt, int* __restrict__ bsum) {
    __shared__ int ls[256];
    int t = threadIdx.x;
    ls[t] = ecnt[blockIdx.x * 256 + t];
    __syncthreads();
    for (int d = 128; d > 0; d >>= 1) { if (t < d) ls[t] += ls[t + d]; __syncthreads(); }
    if (t == 0) bsum[blockIdx.x] = ls[0];
}

__global__ void k_scan2(int* __restrict__ bsum) {  // 1 block, 2048 elems
    __shared__ int ls[256];
    int t = threadIdx.x;
    int loc[8]; int s = 0;
#pragma unroll
    for (int i = 0; i < 8; i++) { loc[i] = bsum[t * 8 + i]; s += loc[i]; }
    ls[t] = s; __syncthreads();
    for (int d = 1; d < 256; d <<= 1) {
        int add = (t >= d) ? ls[t - d] : 0; __syncthreads();
        ls[t] += add; __syncthreads();
    }
    int run = ls[t] - s;  // exclusive
#pragma unroll
    for (int i = 0; i < 8; i++) { int tmp = loc[i]; bsum[t * 8 + i] = run; run += tmp; }
}

__global__ void k_scan3(const int* __restrict__ ecnt, const int* __restrict__ bsum,
                        int* __restrict__ offs) {
    __shared__ int ls[256];
    int t = threadIdx.x, n = blockIdx.x * 256 + t;
    int v = ecnt[n];
    ls[t] = v; __syncthreads();
    for (int d = 1; d < 256; d <<= 1) {
        int add = (t >= d) ? ls[t - d] : 0; __syncthreads();
        ls[t] += add; __syncthreads();
    }
    offs[n] = bsum[blockIdx.x] + ls[t] - v;
    if (n == 0) offs[NN] = NE;
}

// ---------------- CSR fill + fused pre_val materialization ----------------
__global__ void k_fill(const int* __restrict__ ei, const int* __restrict__ offs,
                       int* __restrict__ cursor, int* __restrict__ csr,
                       const float2* __restrict__ f2a, float* __restrict__ pre_val) {
    int e = blockIdx.x * 256 + threadIdx.x;
    int r = ei[e], c = ei[NE + e];
    int p = atomicAdd(&cursor[c], 1);
    int slot = offs[c] + p;
    csr[slot] = r;
    pre_val[slot] = f2a[r].x;
}

// ---------------- pass A: s[c] = dinv_c*(sum pre_val + dinv_c x_c); sd={s,dinv} ----------
__global__ void k_sg(const int* __restrict__ offs, const float* __restrict__ pre_val,
                     const float2* __restrict__ f2a, float2* __restrict__ sd) {
    int n = blockIdx.x * 256 + threadIdx.x;
    int a = offs[n], b = offs[n + 1];
    float2 me = f2a[n];
    float sum = me.x;
    for (int e = a; e < b; e += 4) {
#pragma unroll
        for (int i = 0; i < 4; i++) {
            int ee = e + i;
            float v = pre_val[min(ee, b - 1)];
            sum += (ee < b) ? v : 0.0f;
        }
    }
    sd[n] = make_float2(me.y * sum, me.y);
}

// ---------------- materialize val[e] = sd[csr[e]] (thread-parallel random gather) --------
__global__ void k_val(const int* __restrict__ csr, const float2* __restrict__ sd,
                      float2* __restrict__ val) {
    int e = blockIdx.x * 256 + threadIdx.x;
    val[e] = sd[csr[e]];
}

// ---------------- gather: aggB[n][j] = bf16( dinv_n*(self + sum_e dinv_r x1_r) ) ---------
// predicated unroll-by-4: 4 independent loads in flight, no serial remainder
__global__ __launch_bounds__(256) void k_gather(
        const int* __restrict__ offs, const float2* __restrict__ val,
        const float2* __restrict__ sd, const float* __restrict__ W1,
        const float* __restrict__ b1, unsigned short* __restrict__ aggB) {
    int t = threadIdx.x;
    int wv = t >> 6, j = t & 63;
    int n = blockIdx.x * 4 + wv;
    float w1j = W1[j], b1j = b1[j];
    int a = offs[n], bnd = offs[n + 1];
    float2 sdn = sd[n];
    float x1 = fmaxf(fmaf(sdn.x, w1j, b1j), 0.0f);
    float acc = sdn.y * x1;  // self-loop term
    for (int e = a; e < bnd; e += 4) {
#pragma unroll
        for (int i = 0; i < 4; i++) {
            int ee = e + i;
            float2 v = val[min(ee, bnd - 1)];
            float wgt = (ee < bnd) ? v.y : 0.0f;
            acc = fmaf(wgt, fmaxf(fmaf(v.x, w1j, b1j), 0.0f), acc);
        }
    }
    aggB[(size_t)n * GH + j] = f2bf(sdn.y * acc);
}

// ---------------- MFMA: x2 = relu(aggB @ W2 + b2); pool into sums ----------------
__global__ __launch_bounds__(256) void k_x2pool(
        const unsigned short* __restrict__ aggB, const unsigned short* __restrict__ W2T,
        const float* __restrict__ b2, const int* __restrict__ batch,
        float* __restrict__ sums) {
    int t = threadIdx.x;
    int wv = t >> 6, lane = t & 63;
    int lg = lane >> 4, lr = lane & 15;
    int n0 = blockIdx.x * 64 + wv * 16;

    bf16x8 a0 = *reinterpret_cast<const bf16x8*>(aggB + (size_t)(n0 + lr) * GH + lg * 8);
    bf16x8 a1 = *reinterpret_cast<const bf16x8*>(aggB + (size_t)(n0 + lr) * GH + 32 + lg * 8);

    f32x4 acc[4];
#pragma unroll
    for (int jt = 0; jt < 4; jt++) acc[jt] = (f32x4){0.f, 0.f, 0.f, 0.f};
#pragma unroll
    for (int jt = 0; jt < 4; jt++) {
        bf16x8 b0 = *reinterpret_cast<const bf16x8*>(W2T + (jt * 16 + lr) * GH + lg * 8);
        bf16x8 b1 = *reinterpret_cast<const bf16x8*>(W2T + (jt * 16 + lr) * GH + 32 + lg * 8);
        acc[jt] = __builtin_amdgcn_mfma_f32_16x16x32_bf16(a0, b0, acc[jt], 0, 0, 0);
        acc[jt] = __builtin_amdgcn_mfma_f32_16x16x32_bf16(a1, b1, acc[jt], 0, 0, 0);
    }

    int g0 = batch[n0];
    if (g0 == batch[n0 + 15]) {  // whole 16-node tile in one graph: reduce, 1/16 atomics
#pragma unroll
        for (int jt = 0; jt < 4; jt++) {
            float v = 0.0f;
            float bj = b2[jt * 16 + lr];
#pragma unroll
            for (int r = 0; r < 4; r++) v += fmaxf(acc[jt][r] + bj, 0.0f);
            v += __shfl_xor(v, 16);
            v += __shfl_xor(v, 32);
            if (lane < 16) atomicAdd(&sums[g0 * GH + jt * 16 + lr], v);
        }
    } else {
#pragma unroll
        for (int jt = 0; jt < 4; jt++) {
            float bj = b2[jt * 16 + lr];
#pragma unroll
            for (int r = 0; r < 4; r++) {
                int node = n0 + lg * 4 + r;
                int g = batch[node];
                atomicAdd(&sums[g * GH + jt * 16 + lr], fmaxf(acc[jt][r] + bj, 0.0f));
            }
        }
    }
}

// ---------------- per-graph: pooled = sums/cnt; gemb = pooled @ Wg + bg ----------------
__global__ void k_graph(const float* __restrict__ sums, const float* __restrict__ cnt,
                        const float* __restrict__ Wg, const float* __restrict__ bg,
                        float* __restrict__ gemb) {
    __shared__ float wgs[GH * GE];   // 32 KB
    __shared__ float ps[4 * GH];
    int t = threadIdx.x;
    for (int i = t; i < GH * GE; i += 256) wgs[i] = Wg[i];
    int gid = blockIdx.x * 256 + t;
    int g = gid >> 6, j = t & 63, w = t >> 6;
    float c = fmaxf(cnt[g], 1.0f);
    ps[t] = sums[g * GH + j] / c;
    __syncthreads();
    float o0 = bg[j], o1 = bg[GH + j];
#pragma unroll
    for (int k = 0; k < GH; k++) {
        float p = ps[w * GH + k];
        o0 = fmaf(p, wgs[k * GE + j], o0);
        o1 = fmaf(p, wgs[k * GE + GH + j], o1);
    }
    gemb[g * GE + j] = o0;
    gemb[g * GE + GH + j] = o1;
}

// ---------------- transpose+convert Wf1 -> WT bf16; block 1024 builds W2T ----------------
__global__ void k_wt(const float* __restrict__ Wf1, unsigned short* __restrict__ WT,
                     const float* __restrict__ W2, unsigned short* __restrict__ W2T) {
    if (blockIdx.x == 1024) {  // W2T[j][k] = bf16(W2[k][j]), 64x64
        int t = threadIdx.x;
        for (int i = 0; i < 16; i++) {
            int idx = t * 16 + i;
            int j = idx >> 6, k = idx & 63;
            W2T[j * GH + k] = f2bf(W2[k * GH + j]);
        }
        return;
    }
    __shared__ float tl[32][33];
    int bk = blockIdx.x & 127;
    int bn = blockIdx.x >> 7;
    int tx = threadIdx.x & 31, ty = threadIdx.x >> 5;  // 32 x 8
    int k0 = bk * 32, n0 = bn * 32;
#pragma unroll
    for (int i = 0; i < 4; i++) {
        int k = k0 + ty + i * 8;
        tl[ty + i * 8][tx] = (k < KD) ? Wf1[k * HIDD + n0 + tx] : 0.0f;
    }
    __syncthreads();
#pragma unroll
    for (int i = 0; i < 4; i++) {
        int n = n0 + ty + i * 8;
        WT[n * KP + k0 + tx] = f2bf(tl[tx][ty + i * 8]);
    }
}

// ---------------- build combined [NG][KP] bf16 (zero-padded), 8 elems/thread ----------------
__global__ void k_comb(const float* __restrict__ gemb, const float* __restrict__ comp,
                       const float* __restrict__ prot, unsigned short* __restrict__ comb) {
    size_t t = ((size_t)blockIdx.x * 256 + threadIdx.x) * 8;
    int g = (int)(t >> 12), k0 = (int)(t & (KP - 1));
    u16x8 r;
#pragma unroll
    for (int i = 0; i < 8; i++) {
        int k = k0 + i;
        float v = 0.0f;
        if (k < GE) v = gemb[g * GE + k];
        else if (k < GE + CDIM) v = comp[(size_t)g * CDIM + (k - GE)];
        else if (k < KD) v = prot[g * PDIM + (k - GE - CDIM)];
        r[i] = f2bf(v);
    }
    *reinterpret_cast<u16x8*>(comb + t) = r;
}

// ---------------- MFMA head GEMM: out = sigmoid(relu(comb@Wf1+bf1)@Wf2+bf2) ----------------
__global__ __launch_bounds__(256) void k_gemm_mfma(
        const unsigned short* __restrict__ WT, const unsigned short* __restrict__ comb,
        const float* __restrict__ bf1, const float* __restrict__ Wf2,
        const float* __restrict__ bf2, float* __restrict__ out) {
    __shared__ float red[32];
    int t = threadIdx.x;
    int wv = t >> 6, lane = t & 63;
    int lg = lane >> 4, lr = lane & 15;
    int g0 = blockIdx.x * 32;

    const unsigned short* wbase = WT + (size_t)(wv * 64 + lr) * KP + lg * 8;
    const unsigned short* cbase = comb + (size_t)(g0 + lr) * KP + lg * 8;

    f32x4 acc[4][2];
#pragma unroll
    for (int i = 0; i < 4; i++)
#pragma unroll
        for (int j = 0; j < 2; j++) acc[i][j] = (f32x4){0.f, 0.f, 0.f, 0.f};

    bf16x8 a[4], b[2], an[4], bn[2];
#pragma unroll
    for (int nt = 0; nt < 4; nt++) a[nt] = *reinterpret_cast<const bf16x8*>(wbase + nt * 16 * KP);
#pragma unroll
    for (int gt = 0; gt < 2; gt++) b[gt] = *reinterpret_cast<const bf16x8*>(cbase + gt * 16 * KP);

#pragma unroll 1
    for (int k = 32; k <= KLOOP; k += 32) {
        if (k < KLOOP) {
#pragma unroll
            for (int nt = 0; nt < 4; nt++)
                an[nt] = *reinterpret_cast<const bf16x8*>(wbase + nt * 16 * KP + k);
#pragma unroll
            for (int gt = 0; gt < 2; gt++)
                bn[gt] = *reinterpret_cast<const bf16x8*>(cbase + gt * 16 * KP + k);
        }
#pragma unroll
        for (int nt = 0; nt < 4; nt++)
#pragma unroll
            for (int gt = 0; gt < 2; gt++)
                acc[nt][gt] = __builtin_amdgcn_mfma_f32_16x16x32_bf16(a[nt], b[gt], acc[nt][gt], 0, 0, 0);
#pragma unroll
        for (int nt = 0; nt < 4; nt++) a[nt] = an[nt];
#pragma unroll
        for (int gt = 0; gt < 2; gt++) b[gt] = bn[gt];
    }

    if (t < 32) red[t] = 0.0f;
    __syncthreads();
    float bf2c = bf2[0];
#pragma unroll
    for (int gt = 0; gt < 2; gt++) {
        float pv = 0.0f;
#pragma unroll
        for (int nt = 0; nt < 4; nt++) {
            int nb = wv * 64 + nt * 16 + lg * 4;
#pragma unroll
            for (int r = 0; r < 4; r++) {
                float h = fmaxf(acc[nt][gt][r] + bf1[nb + r], 0.0f);
                pv = fmaf(h, Wf2[nb + r], pv);
            }
        }
        pv += __shfl_xor(pv, 16);
        pv += __shfl_xor(pv, 32);
        if (lane < 16) atomicAdd(&red[gt * 16 + lane], pv);
    }
    __syncthreads();
    if (t < 32) out[g0 + t] = 1.0f / (1.0f + expf(-(red[t] + bf2c)));
}

extern "C" void kernel_launch(void* const* d_in, const int* in_sizes, int n_in,
                              void* d_out, int out_size, void* d_ws, size_t ws_size,
                              hipStream_t stream) {
    const float* node_x = (const float*)d_in[0];
    const float* comp   = (const float*)d_in[1];
    const float* prot   = (const float*)d_in[2];
    const int*   ei     = (const int*)d_in[3];
    const int*   batch  = (const int*)d_in[4];
    const float* W1  = (const float*)d_in[5];
    const float* b1  = (const float*)d_in[6];
    const float* W2  = (const float*)d_in[7];
    const float* b2  = (const float*)d_in[8];
    const float* Wg  = (const float*)d_in[9];
    const float* bg  = (const float*)d_in[10];
    const float* Wf1 = (const float*)d_in[11];
    const float* bf1 = (const float*)d_in[12];
    const float* Wf2 = (const float*)d_in[13];
    const float* bf2 = (const float*)d_in[14];
    float* out = (float*)d_out;

    // -------- workspace layout (≈138.0 MiB; region A [0,134MB) becomes comb at k_comb) ----
    char* W = (char*)d_ws;
    unsigned short* comb = (unsigned short*)W;
    float*  deg     = (float*)(W + 0);          // NN f32 (dead after k_prep)
    float2* f2a     = (float2*)(W + 2097152);   // NN float2
    float2* sd      = (float2*)(W + 6291456);   // NN float2
    int*    ecnt    = (int*)(W + 10485760);     // NN int
    int*    offs    = (int*)(W + 12582912);     // NN+1 int
    int*    cursor  = (int*)(W + 14680320);     // NN int
    int*    bsum    = (int*)(W + 16777728);     // 2048 int
    int*    csr     = (int*)(W + 16786432);     // NE int
    float*  sums    = (float*)(W + 25175040);   // NG*64 f32
    float*  cnt     = (float*)(W + 29369344);   // NG f32
    float*  pre_val = (float*)(W + 33554432);   // NE f32
    float2* val     = (float2*)(W + 41943040);  // NE float2
    unsigned short* aggB = (unsigned short*)(W + 58720256);  // NN*64 bf16 (67 MB)
    // Region B/C (live to the end):
    float*  gemb    = (float*)(W + 134217728);              // NG*128 f32
    unsigned short* WT  = (unsigned short*)(W + 142606336); // 256*KP bf16
    unsigned short* W2T = (unsigned short*)(W + 144703488); // 64*64 bf16

    k_init<<<4096, 256, 0, stream>>>(deg, cursor, sums);
    k_deg<<<NE / 256, 256, 0, stream>>>(ei, deg);
    k_prep<<<NN / 256, 256, 0, stream>>>(node_x, deg, f2a, ecnt);
    k_cnt<<<NG / 256, 256, 0, stream>>>(batch, cnt);
    k_scan1<<<NN / 256, 256, 0, stream>>>(ecnt, bsum);
    k_scan2<<<1, 256, 0, stream>>>(bsum);
    k_scan3<<<NN / 256, 256, 0, stream>>>(ecnt, bsum, offs);
    k_fill<<<NE / 256, 256, 0, stream>>>(ei, offs, cursor, csr, f2a, pre_val);
    k_sg<<<NN / 256, 256, 0, stream>>>(offs, pre_val, f2a, sd);
    k_val<<<NE / 256, 256, 0, stream>>>(csr, sd, val);
    k_gather<<<NN / 4, 256, 0, stream>>>(offs, val, sd, W1, b1, aggB);
    k_x2pool<<<NN / 64, 256, 0, stream>>>(aggB, W2T, b2, batch, sums);
    k_graph<<<NG * GH / 256, 256, 0, stream>>>(sums, cnt, Wg, bg, gemb);
    k_wt<<<1025, 256, 0, stream>>>(Wf1, WT, W2, W2T);
    k_comb<<<NG * KP / (256 * 8), 256, 0, stream>>>(gemb, comp, prot, comb);
    k_gemm_mfma<<<NG / 32, 256, 0, stream>>>(WT, comb, bf1, Wf2, bf2, out);
}

// Round 6
// 795.045 us; speedup vs baseline: 3.1352x; 1.2079x over previous
//
#include <hip/hip_runtime.h>

#define NN 524288
#define NE 2097152
#define NG 16384
#define CDIM 3539
#define PDIM 384
#define GH 64
#define GE 128
#define HIDD 256
#define KD (GE + CDIM + PDIM)  // 4051
#define KP 4096                // padded K stride (bf16 elems)
#define KLOOP 4064             // 127*32 >= KD, multiple of 32

typedef short bf16x8 __attribute__((ext_vector_type(8)));
typedef unsigned short u16x8 __attribute__((ext_vector_type(8)));
typedef float f32x4 __attribute__((ext_vector_type(4)));

__device__ inline unsigned short f2bf(float f) {
    unsigned int u = __float_as_uint(f);
    u += 0x7FFF + ((u >> 16) & 1);  // RNE
    return (unsigned short)(u >> 16);
}

// ---------------- init: deg=1 (self-loop), cursor=0, zero sums ----------------
__global__ void k_init(float* __restrict__ deg, int* __restrict__ cursor,
                       float* __restrict__ sums) {
    int i = blockIdx.x * blockDim.x + threadIdx.x;
    if (i < NN) { deg[i] = 1.0f; cursor[i] = 0; }
    if (i < NG * GH) sums[i] = 0.0f;
}

// ---------------- in-degree histogram over col ----------------
__global__ void k_deg(const int* __restrict__ ei, float* __restrict__ deg) {
    int e = blockIdx.x * blockDim.x + threadIdx.x;
    if (e < NE) atomicAdd(&deg[ei[NE + e]], 1.0f);
}

// ---------------- dinv, f2a = {dinv*x, dinv}, integer edge counts ----------------
__global__ void k_prep(const float* __restrict__ node_x, const float* __restrict__ deg,
                       float2* __restrict__ f2a, int* __restrict__ ecnt) {
    int n = blockIdx.x * blockDim.x + threadIdx.x;
    float d = deg[n];
    float di = rsqrtf(d);
    f2a[n] = make_float2(di * node_x[n], di);
    ecnt[n] = (int)(d - 0.5f);  // d = count + 1.0 exactly
}

// ---------------- cnt[g] via binary search on sorted batch ----------------
__global__ void k_cnt(const int* __restrict__ batch, float* __restrict__ cnt) {
    int g = blockIdx.x * 256 + threadIdx.x;  // NG threads
    int lo = 0, hi = NN;
    while (lo < hi) { int mid = (lo + hi) >> 1; if (batch[mid] < g) lo = mid + 1; else hi = mid; }
    int lo2 = lo, hi2 = NN;
    while (lo2 < hi2) { int mid = (lo2 + hi2) >> 1; if (batch[mid] < g + 1) lo2 = mid + 1; else hi2 = mid; }
    cnt[g] = (float)(lo2 - lo);
}

// ---------------- 3-kernel exclusive scan of ecnt[NN] -> offs[NN+1] ----------------
__global__ void k_scan1(const int* __restrict__ ecnt, int* __restrict__ bsum) {
    __shared__ int ls[256];
    int t = threadIdx.x;
    ls[t] = ecnt[blockIdx.x * 256 + t];
    __syncthreads();
    for (int d = 128; d > 0; d >>= 1) { if (t < d) ls[t] += ls[t + d]; __syncthreads(); }
    if (t == 0) bsum[blockIdx.x] = ls[0];
}

__global__ void k_scan2(int* __restrict__ bsum) {  // 1 block, 2048 elems
    __shared__ int ls[256];
    int t = threadIdx.x;
    int loc[8]; int s = 0;
#pragma unroll
    for (int i = 0; i < 8; i++) { loc[i] = bsum[t * 8 + i]; s += loc[i]; }
    ls[t] = s; __syncthreads();
    for (int d = 1; d < 256; d <<= 1) {
        int add = (t >= d) ? ls[t - d] : 0; __syncthreads();
        ls[t] += add; __syncthreads();
    }
    int run = ls[t] - s;  // exclusive
#pragma unroll
    for (int i = 0; i < 8; i++) { int tmp = loc[i]; bsum[t * 8 + i] = run; run += tmp; }
}

__global__ void k_scan3(const int* __restrict__ ecnt, const int* __restrict__ bsum,
                        int* __restrict__ offs) {
    __shared__ int ls[256];
    int t = threadIdx.x, n = blockIdx.x * 256 + t;
    int v = ecnt[n];
    ls[t] = v; __syncthreads();
    for (int d = 1; d < 256; d <<= 1) {
        int add = (t >= d) ? ls[t - d] : 0; __syncthreads();
        ls[t] += add; __syncthreads();
    }
    offs[n] = bsum[blockIdx.x] + ls[t] - v;
    if (n == 0) offs[NN] = NE;
}

// ---------------- CSR fill + fused pre_val materialization ----------------
__global__ void k_fill(const int* __restrict__ ei, const int* __restrict__ offs,
                       int* __restrict__ cursor, int* __restrict__ csr,
                       const float2* __restrict__ f2a, float* __restrict__ pre_val) {
    int e = blockIdx.x * 256 + threadIdx.x;
    int r = ei[e], c = ei[NE + e];
    int p = atomicAdd(&cursor[c], 1);
    int slot = offs[c] + p;
    csr[slot] = r;
    pre_val[slot] = f2a[r].x;
}

// ---------------- pass A: s[c] = dinv_c*(sum pre_val + dinv_c x_c); sd={s,dinv} ----------
__global__ void k_sg(const int* __restrict__ offs, const float* __restrict__ pre_val,
                     const float2* __restrict__ f2a, float2* __restrict__ sd) {
    int n = blockIdx.x * 256 + threadIdx.x;
    int a = offs[n], b = offs[n + 1];
    float2 me = f2a[n];
    float sum = me.x;
    for (int e = a; e < b; e += 4) {
#pragma unroll
        for (int i = 0; i < 4; i++) {
            int ee = e + i;
            float v = pre_val[min(ee, b - 1)];
            sum += (ee < b) ? v : 0.0f;
        }
    }
    sd[n] = make_float2(me.y * sum, me.y);
}

// ---------------- materialize val[e] = sd[csr[e]] (thread-parallel random gather) --------
__global__ void k_val(const int* __restrict__ csr, const float2* __restrict__ sd,
                      float2* __restrict__ val) {
    int e = blockIdx.x * 256 + threadIdx.x;
    val[e] = sd[csr[e]];
}

// ================= FUSED: gather -> W2 MFMA -> relu -> segmented pool ====================
// Block = 64 consecutive nodes, 4 waves. Wave w owns nodes [n0+16w, n0+16w+16).
// Phase 1: serial edge-gather per node (lane = feature j), agg rows -> LDS bf16.
// Phase 2: per-wave MFMA of its 16x64 tile vs W2T (same mapping as old k_x2pool).
// Phase 3: segmented reduction over sorted batch; ~3 coalesced wave-atomics per block.
__global__ __launch_bounds__(256) void k_gx2(
        const int* __restrict__ offs, const float2* __restrict__ val,
        const float2* __restrict__ sd, const float* __restrict__ W1,
        const float* __restrict__ b1, const unsigned short* __restrict__ W2T,
        const float* __restrict__ b2, const int* __restrict__ batch,
        float* __restrict__ sums) {
    __shared__ unsigned short aggs[64][72];  // 9.2 KB, stride 72 -> 2-way banks (free)
    __shared__ float x2s[64][72];            // 18.4 KB
    __shared__ int bloc[64];
    int t = threadIdx.x;
    int wv = t >> 6, lane = t & 63;
    int n0 = blockIdx.x * 64;
    int nw = n0 + wv * 16;
    if (t < 64) bloc[t] = batch[n0 + t];
    float w1j = W1[lane], b1j = b1[lane];
    // per-lane prefetch of offs/sd for the wave's 16 nodes; broadcast via shfl
    int nl = nw + (lane & 15);
    int aL = offs[nl], bndL = offs[nl + 1];
    float2 sdL = sd[nl];
    for (int i = 0; i < 16; i++) {
        int a    = __shfl(aL, i, 64);
        int bnd  = __shfl(bndL, i, 64);
        float sx = __shfl(sdL.x, i, 64);
        float sy = __shfl(sdL.y, i, 64);
        float acc = sy * fmaxf(fmaf(sx, w1j, b1j), 0.0f);  // self-loop
        for (int e = a; e < bnd; e += 4) {
#pragma unroll
            for (int u = 0; u < 4; u++) {
                int ee = e + u;
                float2 v = val[min(ee, bnd - 1)];
                float wgt = (ee < bnd) ? v.y : 0.0f;
                acc = fmaf(wgt, fmaxf(fmaf(v.x, w1j, b1j), 0.0f), acc);
            }
        }
        aggs[wv * 16 + i][lane] = f2bf(sy * acc);
    }
    __syncthreads();
    // phase 2: MFMA W2 transform (wave reads only its own 16 rows)
    int lg = lane >> 4, lr = lane & 15;
    bf16x8 a0 = *reinterpret_cast<const bf16x8*>(&aggs[wv * 16 + lr][lg * 8]);
    bf16x8 a1 = *reinterpret_cast<const bf16x8*>(&aggs[wv * 16 + lr][32 + lg * 8]);
    f32x4 acc4[4];
#pragma unroll
    for (int jt = 0; jt < 4; jt++) acc4[jt] = (f32x4){0.f, 0.f, 0.f, 0.f};
#pragma unroll
    for (int jt = 0; jt < 4; jt++) {
        bf16x8 b0 = *reinterpret_cast<const bf16x8*>(W2T + (jt * 16 + lr) * GH + lg * 8);
        bf16x8 b1v = *reinterpret_cast<const bf16x8*>(W2T + (jt * 16 + lr) * GH + 32 + lg * 8);
        acc4[jt] = __builtin_amdgcn_mfma_f32_16x16x32_bf16(a0, b0, acc4[jt], 0, 0, 0);
        acc4[jt] = __builtin_amdgcn_mfma_f32_16x16x32_bf16(a1, b1v, acc4[jt], 0, 0, 0);
    }
#pragma unroll
    for (int jt = 0; jt < 4; jt++) {
        float bj = b2[jt * 16 + lr];
#pragma unroll
        for (int r = 0; r < 4; r++)
            x2s[wv * 16 + lg * 4 + r][jt * 16 + lr] = fmaxf(acc4[jt][r] + bj, 0.0f);
    }
    __syncthreads();
    // phase 3: segmented reduction (batch sorted -> contiguous runs); wave-uniform control
    for (int i = wv; i < 64; i += 4) {
        bool isStart = (i == 0) || (bloc[i] != bloc[i - 1]);
        if (isStart) {
            int g = bloc[i];
            float s = 0.0f;
            int k = i;
            do { s += x2s[k][lane]; k++; } while (k < 64 && bloc[k] == g);
            atomicAdd(&sums[g * GH + lane], s);
        }
    }
}

// ---------------- per-graph: pooled = sums/cnt; gemb = pooled @ Wg + bg ----------------
__global__ void k_graph(const float* __restrict__ sums, const float* __restrict__ cnt,
                        const float* __restrict__ Wg, const float* __restrict__ bg,
                        float* __restrict__ gemb) {
    __shared__ float wgs[GH * GE];   // 32 KB
    __shared__ float ps[4 * GH];
    int t = threadIdx.x;
    for (int i = t; i < GH * GE; i += 256) wgs[i] = Wg[i];
    int gid = blockIdx.x * 256 + t;
    int g = gid >> 6, j = t & 63, w = t >> 6;
    float c = fmaxf(cnt[g], 1.0f);
    ps[t] = sums[g * GH + j] / c;
    __syncthreads();
    float o0 = bg[j], o1 = bg[GH + j];
#pragma unroll
    for (int k = 0; k < GH; k++) {
        float p = ps[w * GH + k];
        o0 = fmaf(p, wgs[k * GE + j], o0);
        o1 = fmaf(p, wgs[k * GE + GH + j], o1);
    }
    gemb[g * GE + j] = o0;
    gemb[g * GE + GH + j] = o1;
}

// ---------------- transpose+convert Wf1 -> WT bf16; block 1024 builds W2T ----------------
__global__ void k_wt(const float* __restrict__ Wf1, unsigned short* __restrict__ WT,
                     const float* __restrict__ W2, unsigned short* __restrict__ W2T) {
    if (blockIdx.x == 1024) {  // W2T[j][k] = bf16(W2[k][j]), 64x64
        int t = threadIdx.x;
        for (int i = 0; i < 16; i++) {
            int idx = t * 16 + i;
            int j = idx >> 6, k = idx & 63;
            W2T[j * GH + k] = f2bf(W2[k * GH + j]);
        }
        return;
    }
    __shared__ float tl[32][33];
    int bk = blockIdx.x & 127;
    int bn = blockIdx.x >> 7;
    int tx = threadIdx.x & 31, ty = threadIdx.x >> 5;  // 32 x 8
    int k0 = bk * 32, n0 = bn * 32;
#pragma unroll
    for (int i = 0; i < 4; i++) {
        int k = k0 + ty + i * 8;
        tl[ty + i * 8][tx] = (k < KD) ? Wf1[k * HIDD + n0 + tx] : 0.0f;
    }
    __syncthreads();
#pragma unroll
    for (int i = 0; i < 4; i++) {
        int n = n0 + ty + i * 8;
        WT[n * KP + k0 + tx] = f2bf(tl[tx][ty + i * 8]);
    }
}

// ---------------- build combined [NG][KP] bf16 (zero-padded), 8 elems/thread ----------------
__global__ void k_comb(const float* __restrict__ gemb, const float* __restrict__ comp,
                       const float* __restrict__ prot, unsigned short* __restrict__ comb) {
    size_t t = ((size_t)blockIdx.x * 256 + threadIdx.x) * 8;
    int g = (int)(t >> 12), k0 = (int)(t & (KP - 1));
    u16x8 r;
#pragma unroll
    for (int i = 0; i < 8; i++) {
        int k = k0 + i;
        float v = 0.0f;
        if (k < GE) v = gemb[g * GE + k];
        else if (k < GE + CDIM) v = comp[(size_t)g * CDIM + (k - GE)];
        else if (k < KD) v = prot[g * PDIM + (k - GE - CDIM)];
        r[i] = f2bf(v);
    }
    *reinterpret_cast<u16x8*>(comb + t) = r;
}

// ---------------- MFMA head GEMM: out = sigmoid(relu(comb@Wf1+bf1)@Wf2+bf2) ----------------
__global__ __launch_bounds__(256) void k_gemm_mfma(
        const unsigned short* __restrict__ WT, const unsigned short* __restrict__ comb,
        const float* __restrict__ bf1, const float* __restrict__ Wf2,
        const float* __restrict__ bf2, float* __restrict__ out) {
    __shared__ float red[32];
    int t = threadIdx.x;
    int wv = t >> 6, lane = t & 63;
    int lg = lane >> 4, lr = lane & 15;
    int g0 = blockIdx.x * 32;

    const unsigned short* wbase = WT + (size_t)(wv * 64 + lr) * KP + lg * 8;
    const unsigned short* cbase = comb + (size_t)(g0 + lr) * KP + lg * 8;

    f32x4 acc[4][2];
#pragma unroll
    for (int i = 0; i < 4; i++)
#pragma unroll
        for (int j = 0; j < 2; j++) acc[i][j] = (f32x4){0.f, 0.f, 0.f, 0.f};

    bf16x8 a[4], b[2], an[4], bn[2];
#pragma unroll
    for (int nt = 0; nt < 4; nt++) a[nt] = *reinterpret_cast<const bf16x8*>(wbase + nt * 16 * KP);
#pragma unroll
    for (int gt = 0; gt < 2; gt++) b[gt] = *reinterpret_cast<const bf16x8*>(cbase + gt * 16 * KP);

#pragma unroll 1
    for (int k = 32; k <= KLOOP; k += 32) {
        if (k < KLOOP) {
#pragma unroll
            for (int nt = 0; nt < 4; nt++)
                an[nt] = *reinterpret_cast<const bf16x8*>(wbase + nt * 16 * KP + k);
#pragma unroll
            for (int gt = 0; gt < 2; gt++)
                bn[gt] = *reinterpret_cast<const bf16x8*>(cbase + gt * 16 * KP + k);
        }
#pragma unroll
        for (int nt = 0; nt < 4; nt++)
#pragma unroll
            for (int gt = 0; gt < 2; gt++)
                acc[nt][gt] = __builtin_amdgcn_mfma_f32_16x16x32_bf16(a[nt], b[gt], acc[nt][gt], 0, 0, 0);
#pragma unroll
        for (int nt = 0; nt < 4; nt++) a[nt] = an[nt];
#pragma unroll
        for (int gt = 0; gt < 2; gt++) b[gt] = bn[gt];
    }

    if (t < 32) red[t] = 0.0f;
    __syncthreads();
    float bf2c = bf2[0];
#pragma unroll
    for (int gt = 0; gt < 2; gt++) {
        float pv = 0.0f;
#pragma unroll
        for (int nt = 0; nt < 4; nt++) {
            int nb = wv * 64 + nt * 16 + lg * 4;
#pragma unroll
            for (int r = 0; r < 4; r++) {
                float h = fmaxf(acc[nt][gt][r] + bf1[nb + r], 0.0f);
                pv = fmaf(h, Wf2[nb + r], pv);
            }
        }
        pv += __shfl_xor(pv, 16);
        pv += __shfl_xor(pv, 32);
        if (lane < 16) atomicAdd(&red[gt * 16 + lane], pv);
    }
    __syncthreads();
    if (t < 32) out[g0 + t] = 1.0f / (1.0f + expf(-(red[t] + bf2c)));
}

extern "C" void kernel_launch(void* const* d_in, const int* in_sizes, int n_in,
                              void* d_out, int out_size, void* d_ws, size_t ws_size,
                              hipStream_t stream) {
    const float* node_x = (const float*)d_in[0];
    const float* comp   = (const float*)d_in[1];
    const float* prot   = (const float*)d_in[2];
    const int*   ei     = (const int*)d_in[3];
    const int*   batch  = (const int*)d_in[4];
    const float* W1  = (const float*)d_in[5];
    const float* b1  = (const float*)d_in[6];
    const float* W2  = (const float*)d_in[7];
    const float* b2  = (const float*)d_in[8];
    const float* Wg  = (const float*)d_in[9];
    const float* bg  = (const float*)d_in[10];
    const float* Wf1 = (const float*)d_in[11];
    const float* bf1 = (const float*)d_in[12];
    const float* Wf2 = (const float*)d_in[13];
    const float* bf2 = (const float*)d_in[14];
    float* out = (float*)d_out;

    // -------- workspace layout (≈138.0 MiB; region A [0,134MB) becomes comb at k_comb) ----
    char* W = (char*)d_ws;
    unsigned short* comb = (unsigned short*)W;
    float*  deg     = (float*)(W + 0);          // NN f32 (dead after k_prep)
    float2* f2a     = (float2*)(W + 2097152);   // NN float2
    float2* sd      = (float2*)(W + 6291456);   // NN float2
    int*    ecnt    = (int*)(W + 10485760);     // NN int
    int*    offs    = (int*)(W + 12582912);     // NN+1 int
    int*    cursor  = (int*)(W + 14680320);     // NN int
    int*    bsum    = (int*)(W + 16777728);     // 2048 int
    int*    csr     = (int*)(W + 16786432);     // NE int
    float*  sums    = (float*)(W + 25175040);   // NG*64 f32
    float*  cnt     = (float*)(W + 29369344);   // NG f32
    float*  pre_val = (float*)(W + 33554432);   // NE f32
    float2* val     = (float2*)(W + 41943040);  // NE float2
    // Region B/C (live to the end):
    float*  gemb    = (float*)(W + 134217728);              // NG*128 f32
    unsigned short* WT  = (unsigned short*)(W + 142606336); // 256*KP bf16
    unsigned short* W2T = (unsigned short*)(W + 144703488); // 64*64 bf16

    k_init<<<4096, 256, 0, stream>>>(deg, cursor, sums);
    k_wt<<<1025, 256, 0, stream>>>(Wf1, WT, W2, W2T);  // FIRST: W2T/WT ready before use
    k_deg<<<NE / 256, 256, 0, stream>>>(ei, deg);
    k_prep<<<NN / 256, 256, 0, stream>>>(node_x, deg, f2a, ecnt);
    k_cnt<<<NG / 256, 256, 0, stream>>>(batch, cnt);
    k_scan1<<<NN / 256, 256, 0, stream>>>(ecnt, bsum);
    k_scan2<<<1, 256, 0, stream>>>(bsum);
    k_scan3<<<NN / 256, 256, 0, stream>>>(ecnt, bsum, offs);
    k_fill<<<NE / 256, 256, 0, stream>>>(ei, offs, cursor, csr, f2a, pre_val);
    k_sg<<<NN / 256, 256, 0, stream>>>(offs, pre_val, f2a, sd);
    k_val<<<NE / 256, 256, 0, stream>>>(csr, sd, val);
    k_gx2<<<NN / 64, 256, 0, stream>>>(offs, val, sd, W1, b1, W2T, b2, batch, sums);
    k_graph<<<NG * GH / 256, 256, 0, stream>>>(sums, cnt, Wg, bg, gemb);
    k_comb<<<NG * KP / (256 * 8), 256, 0, stream>>>(gemb, comp, prot, comb);
    k_gemm_mfma<<<NG / 32, 256, 0, stream>>>(WT, comb, bf1, Wf2, bf2, out);
}